// Round 1
// baseline (791.384 us; speedup 1.0000x reference)
//
#include <hip/hip_runtime.h>
#include <hip/hip_bf16.h>
#include <math.h>

#define BATCH   2
#define SEQLEN  1024
#define DMODEL  1024
#define DINNER  2048
#define DSTATE  16
#define DTRANK  64
#define XPN     96              // DTRANK + 2*DSTATE
#define MROWS   (BATCH*SEQLEN)  // 2048

// ---------------------------------------------------------------------------
// Generic fp32 GEMM: C[M,N] = A[M,K] @ W[N,K]^T   (both row-major)
// 64x64 tile, 256 threads, 4x4 micro-tile, BK=16, K-split via gridDim.z.
// EPI: 0 = plain float4 store
//      1 = atomicAdd (for K-split partial accumulation), N-bounds-checked
//      2 = softplus(acc + 2*bias[n])  (the double-added dt bias)
// ---------------------------------------------------------------------------
template<int EPI>
__global__ __launch_bounds__(256) void gemm_nt(
    const float* __restrict__ A, int lda,
    const float* __restrict__ W, int ldw,
    float* __restrict__ C, int ldc,
    int N, int K, const float* __restrict__ bias)
{
  __shared__ __align__(16) float As[16][68];   // [k][m], +4 pad keeps 16B align
  __shared__ __align__(16) float Ws[16][68];   // [k][n]
  const int t  = threadIdx.x;
  const int tn = t & 15, tm = t >> 4;
  const int n0 = blockIdx.x * 64, m0 = blockIdx.y * 64;
  const int kchunk = K / gridDim.z;
  const int kbeg = blockIdx.z * kchunk;
  const int kend = kbeg + kchunk;
  const int r  = t >> 2;          // 0..63 (tile row for staging)
  const int c4 = (t & 3) * 4;     // 0,4,8,12 (k offset for staging)

  float acc[4][4] = {};

  for (int k0 = kbeg; k0 < kend; k0 += 16) {
    float4 av = *(const float4*)&A[(size_t)(m0 + r) * lda + k0 + c4];
    float4 wv = make_float4(0.f, 0.f, 0.f, 0.f);
    if (n0 + r < N)
      wv = *(const float4*)&W[(size_t)(n0 + r) * ldw + k0 + c4];
    As[c4+0][r] = av.x; As[c4+1][r] = av.y; As[c4+2][r] = av.z; As[c4+3][r] = av.w;
    Ws[c4+0][r] = wv.x; Ws[c4+1][r] = wv.y; Ws[c4+2][r] = wv.z; Ws[c4+3][r] = wv.w;
    __syncthreads();
#pragma unroll
    for (int kk = 0; kk < 16; ++kk) {
      float4 a4 = *(const float4*)&As[kk][tm * 4];
      float4 b4 = *(const float4*)&Ws[kk][tn * 4];
      float a[4] = {a4.x, a4.y, a4.z, a4.w};
      float b[4] = {b4.x, b4.y, b4.z, b4.w};
#pragma unroll
      for (int i = 0; i < 4; ++i)
#pragma unroll
        for (int j = 0; j < 4; ++j)
          acc[i][j] = fmaf(a[i], b[j], acc[i][j]);
    }
    __syncthreads();
  }

  const int mrow = m0 + tm * 4;
  const int ncol = n0 + tn * 4;
  if constexpr (EPI == 1) {
#pragma unroll
    for (int i = 0; i < 4; ++i)
#pragma unroll
      for (int j = 0; j < 4; ++j)
        if (ncol + j < N)
          atomicAdd(&C[(size_t)(mrow + i) * ldc + ncol + j], acc[i][j]);
  } else if constexpr (EPI == 2) {
#pragma unroll
    for (int i = 0; i < 4; ++i) {
      float4 o;
      float* op = &o.x;
#pragma unroll
      for (int j = 0; j < 4; ++j) {
        float x = acc[i][j] + 2.f * bias[ncol + j];
        op[j] = (x > 20.f) ? x : log1pf(expf(x));
      }
      *(float4*)&C[(size_t)(mrow + i) * ldc + ncol] = o;
    }
  } else {
#pragma unroll
    for (int i = 0; i < 4; ++i) {
      float4 o = make_float4(acc[i][0], acc[i][1], acc[i][2], acc[i][3]);
      *(float4*)&C[(size_t)(mrow + i) * ldc + ncol] = o;
    }
  }
}

// ---------------------------------------------------------------------------
// Causal depthwise conv (k=4) + bias + SiLU.  x = xz[:, :DINNER].
// One thread per (row, d). out[l] = sum_k x[l+k-3]*w[k]  (XLA cross-corr).
// ---------------------------------------------------------------------------
__global__ __launch_bounds__(256) void conv_silu(
    const float* __restrict__ xz,
    const float* __restrict__ conv_w,
    const float* __restrict__ conv_b,
    float* __restrict__ u)
{
  const int idx = blockIdx.x * 256 + threadIdx.x;  // = row*DINNER + d
  const int d   = idx & (DINNER - 1);
  const int row = idx >> 11;           // b*SEQLEN + l
  const int l   = row & (SEQLEN - 1);
  float s = conv_b[d];
#pragma unroll
  for (int k = 0; k < 4; ++k) {
    int lt = l + k - 3;
    if (lt >= 0)
      s = fmaf(xz[(size_t)(row + k - 3) * (2 * DINNER) + d], conv_w[d * 4 + k], s);
  }
  u[idx] = s / (1.f + __expf(-s));     // SiLU
}

// ---------------------------------------------------------------------------
// Selective scan. Block = 256 threads = 16 chains (c) x 16 states (n).
// Grid = 256: block bb -> b = bb>>7, d_base = (bb&127)*16.
// 64-step LDS chunks; per step: s = exp(dv*A)*s + dv*B*u ; y = sum_n s*C
// (16-lane shuffle butterfly); fused +u*D and *silu(z) epilogue.
// ---------------------------------------------------------------------------
__global__ __launch_bounds__(256) void scan_kernel(
    const float* __restrict__ delta,   // [MROWS, DINNER]
    const float* __restrict__ u,       // [MROWS, DINNER]
    const float* __restrict__ xz,      // z = xz[:, DINNER:2*DINNER]
    const float* __restrict__ x_dbl,   // [MROWS, 96]; B at 64..79, C at 80..95
    const float* __restrict__ A_log,   // [DINNER, 16]
    const float* __restrict__ Dp,      // [DINNER]
    float* __restrict__ y_g)           // [MROWS, DINNER]
{
  const int t = threadIdx.x;
  const int c = t >> 4;          // chain within block (0..15)
  const int n = t & 15;          // state index
  const int bb = blockIdx.x;
  const int b = bb >> 7;
  const int d_base = (bb & 127) * 16;
  const int d = d_base + c;

  const float A_dn = -__expf(A_log[d * DSTATE + n]);
  const float Dd = Dp[d];
  float s = 0.f;

  __shared__ __align__(16) float delta_s[64 * 16];
  __shared__ __align__(16) float u_s[64 * 16];
  __shared__ __align__(16) float z_s[64 * 16];
  __shared__ __align__(16) float B_s[64 * 16];
  __shared__ __align__(16) float C_s[64 * 16];
  __shared__ __align__(16) float y_s[64 * 16];

  const int j0 = t * 4;          // 4 consecutive LDS floats per thread
  const int i_st = j0 >> 4;      // staging step index 0..63
  const int cc = j0 & 15;        // staging lane offset 0,4,8,12

  for (int l0 = 0; l0 < SEQLEN; l0 += 64) {
    const int row = b * SEQLEN + l0 + i_st;
    *(float4*)&delta_s[j0] = *(const float4*)&delta[(size_t)row * DINNER + d_base + cc];
    *(float4*)&u_s[j0]     = *(const float4*)&u[(size_t)row * DINNER + d_base + cc];
    *(float4*)&z_s[j0]     = *(const float4*)&xz[(size_t)row * (2 * DINNER) + DINNER + d_base + cc];
    *(float4*)&B_s[j0]     = *(const float4*)&x_dbl[(size_t)row * XPN + DTRANK + cc];
    *(float4*)&C_s[j0]     = *(const float4*)&x_dbl[(size_t)row * XPN + DTRANK + DSTATE + cc];
    __syncthreads();
#pragma unroll 8
    for (int i = 0; i < 64; ++i) {
      float dv = delta_s[i * 16 + c];
      float uv = u_s[i * 16 + c];
      float Bv = B_s[i * 16 + n];
      float Cv = C_s[i * 16 + n];
      float dA = __expf(dv * A_dn);
      s = fmaf(dA, s, dv * Bv * uv);
      float py = s * Cv;
      py += __shfl_xor(py, 1);
      py += __shfl_xor(py, 2);
      py += __shfl_xor(py, 4);
      py += __shfl_xor(py, 8);
      if (n == 0) {
        float zv = z_s[i * 16 + c];
        float yv = py + uv * Dd;
        y_s[i * 16 + c] = yv * (zv / (1.f + __expf(-zv)));
      }
    }
    __syncthreads();
    *(float4*)&y_g[(size_t)row * DINNER + d_base + cc] = *(const float4*)&y_s[j0];
    __syncthreads();
  }
}

// ---------------------------------------------------------------------------
extern "C" void kernel_launch(void* const* d_in, const int* in_sizes, int n_in,
                              void* d_out, int out_size, void* d_ws, size_t ws_size,
                              hipStream_t stream)
{
  const float* hidden     = (const float*)d_in[0];
  const float* in_proj_w  = (const float*)d_in[1];
  const float* conv_w     = (const float*)d_in[2];
  const float* conv_b     = (const float*)d_in[3];
  const float* x_proj_w   = (const float*)d_in[4];
  const float* dt_proj_w  = (const float*)d_in[5];
  const float* dt_proj_b  = (const float*)d_in[6];
  const float* A_log      = (const float*)d_in[7];
  const float* Dp         = (const float*)d_in[8];
  const float* out_proj_w = (const float*)d_in[9];
  float* out = (float*)d_out;

  float* ws    = (float*)d_ws;
  float* xz    = ws;                                        // 2048*4096
  float* u     = xz    + (size_t)MROWS * 2 * DINNER;        // 2048*2048
  float* x_dbl = u     + (size_t)MROWS * DINNER;            // 2048*96
  float* delta = x_dbl + (size_t)MROWS * XPN;               // 2048*2048
  float* y_g   = delta + (size_t)MROWS * DINNER;            // 2048*2048

  // 1. in_proj: xz = hidden @ in_proj_w.T   [2048, 4096]
  gemm_nt<0><<<dim3(2 * DINNER / 64, MROWS / 64, 1), 256, 0, stream>>>(
      hidden, DMODEL, in_proj_w, DMODEL, xz, 2 * DINNER, 2 * DINNER, DMODEL, nullptr);

  // 2. causal depthwise conv + SiLU -> u [2048, 2048]
  conv_silu<<<(MROWS * DINNER) / 256, 256, 0, stream>>>(xz, conv_w, conv_b, u);

  // 3. x_proj: x_dbl = u @ x_proj_w.T  [2048, 96], K-split 8 + atomics
  hipMemsetAsync(x_dbl, 0, (size_t)MROWS * XPN * sizeof(float), stream);
  gemm_nt<1><<<dim3(2, MROWS / 64, 8), 256, 0, stream>>>(
      u, DINNER, x_proj_w, DINNER, x_dbl, XPN, XPN, DINNER, nullptr);

  // 4. dt: delta = softplus(x_dbl[:, :64] @ dt_proj_w.T + 2*dt_proj_b)
  gemm_nt<2><<<dim3(DINNER / 64, MROWS / 64, 1), 256, 0, stream>>>(
      x_dbl, XPN, dt_proj_w, DTRANK, delta, DINNER, DINNER, DTRANK, dt_proj_b);

  // 5. selective scan -> y_g (includes +u*D and *silu(z))
  scan_kernel<<<256, 256, 0, stream>>>(delta, u, xz, x_dbl, A_log, Dp, y_g);

  // 6. out_proj: out = y_g @ out_proj_w.T  [2048, 1024]
  gemm_nt<0><<<dim3(DMODEL / 64, MROWS / 64, 1), 256, 0, stream>>>(
      y_g, DINNER, out_proj_w, DINNER, out, DMODEL, DMODEL, DINNER, nullptr);
}

// Round 2
// 373.278 us; speedup vs baseline: 2.1201x; 2.1201x over previous
//
#include <hip/hip_runtime.h>
#include <hip/hip_bf16.h>
#include <math.h>

#define BATCH   2
#define SEQLEN  1024
#define DMODEL  1024
#define DINNER  2048
#define DSTATE  16
#define DTRANK  64
#define XPAD    128             // padded x_dbl row stride (96 -> 128)
#define MROWS   (BATCH*SEQLEN)  // 2048

typedef float    f32x4  __attribute__((ext_vector_type(4)));
typedef _Float16 f16x8  __attribute__((ext_vector_type(8)));
typedef _Float16 f16x4  __attribute__((ext_vector_type(4)));

#define GLD_LDS(g, l) \
  __builtin_amdgcn_global_load_lds((const __attribute__((address_space(1))) void*)(g), \
                                   (__attribute__((address_space(3))) void*)(l), 16, 0, 0)

// ---------------------------------------------------------------------------
// fp16 MFMA GEMM: C[M,N](fp32) = A[M,K](f16) @ W[N,K](f16)^T
// 128x128 tile, 256 thr (4 waves 2x2), BK=32, 16x16x32 MFMA, 4x4 tiles/wave.
// LDS layout [kb(4)][row(128)][8 halves]: frag ds_read_b128 is <=2-way bank
// aliased (free); staged via global_load_lds width=16 (dest = lane-linear).
// EPI 0: plain fp32 store   1: atomicAdd (split-K)   2: softplus(acc+2*bias)
// EPI 3: fp32 store + f16 copy of cols<64 (x_proj -> dt input)
// ---------------------------------------------------------------------------
template<int EPI>
__global__ __launch_bounds__(256) void hgemm(
    const _Float16* __restrict__ A, int lda,
    const _Float16* __restrict__ W, int ldw,
    float* __restrict__ C, int ldc, int K,
    const float* __restrict__ bias, _Float16* __restrict__ C16)
{
  __shared__ _Float16 As[4096];   // 4 kb * 128 rows * 8 halves
  __shared__ _Float16 Bs[4096];

  const int t  = threadIdx.x;
  const int m0 = blockIdx.y * 128, n0 = blockIdx.x * 128;
  const int kchunk = K / gridDim.z;
  const int kbeg = blockIdx.z * kchunk;

  const _Float16* gA = A + (size_t)(m0 + (t & 127)) * lda + kbeg + (t >> 7) * 8;
  const _Float16* gB = W + (size_t)(n0 + (t & 127)) * ldw + kbeg + (t >> 7) * 8;
  _Float16* lA = As + t * 8;
  _Float16* lB = Bs + t * 8;

  const int lane = t & 63, wvi = t >> 6;
  const int wm = (wvi >> 1) * 64, wn = (wvi & 1) * 64;
  const int lm = lane & 15, lk = lane >> 4;

  f32x4 acc[4][4] = {};

  for (int kk = 0; kk < kchunk; kk += 32) {
    GLD_LDS(gA,      lA);          // kb 0..1
    GLD_LDS(gA + 16, lA + 2048);   // kb 2..3
    GLD_LDS(gB,      lB);
    GLD_LDS(gB + 16, lB + 2048);
    gA += 32; gB += 32;
    __syncthreads();

    f16x8 av[4], bv[4];
#pragma unroll
    for (int i = 0; i < 4; ++i)
      av[i] = *(const f16x8*)&As[lk * 1024 + (wm + i * 16 + lm) * 8];
#pragma unroll
    for (int j = 0; j < 4; ++j)
      bv[j] = *(const f16x8*)&Bs[lk * 1024 + (wn + j * 16 + lm) * 8];
#pragma unroll
    for (int i = 0; i < 4; ++i)
#pragma unroll
      for (int j = 0; j < 4; ++j)
        acc[i][j] = __builtin_amdgcn_mfma_f32_16x16x32_f16(av[i], bv[j], acc[i][j], 0, 0, 0);
    __syncthreads();
  }

  // epilogue: C/D layout col=lane&15, row=(lane>>4)*4+reg (m89/m91-verified)
#pragma unroll
  for (int i = 0; i < 4; ++i) {
    const int mrow = m0 + wm + i * 16 + lk * 4;
#pragma unroll
    for (int j = 0; j < 4; ++j) {
      const int col = n0 + wn + j * 16 + lm;
#pragma unroll
      for (int r = 0; r < 4; ++r) {
        float v = acc[i][j][r];
        size_t off = (size_t)(mrow + r) * ldc + col;
        if constexpr (EPI == 0) {
          C[off] = v;
        } else if constexpr (EPI == 1) {
          atomicAdd(&C[off], v);
        } else if constexpr (EPI == 2) {
          float x = v + 2.f * bias[col];
          C[off] = (x > 20.f) ? x : log1pf(__expf(x));
        } else {  // EPI == 3
          C[off] = v;
          if (col < DTRANK)
            C16[(size_t)(mrow + r) * DTRANK + col] = (_Float16)v;
        }
      }
    }
  }
}

// ---------------------------------------------------------------------------
// fp32 -> fp16 converters
// ---------------------------------------------------------------------------
__global__ __launch_bounds__(256) void f2h(const float* __restrict__ in,
                                           _Float16* __restrict__ out, int n4)
{
  int i = blockIdx.x * 256 + threadIdx.x;
  if (i < n4) {
    float4 v = ((const float4*)in)[i];
    f16x4 h = {(_Float16)v.x, (_Float16)v.y, (_Float16)v.z, (_Float16)v.w};
    ((f16x4*)out)[i] = h;
  }
}

// x_proj_w [96,2048] -> padded f16 [128,2048] (rows 96..127 zero)
__global__ __launch_bounds__(256) void f2h_pad(const float* __restrict__ in,
                                               _Float16* __restrict__ out)
{
  int i = blockIdx.x * 256 + threadIdx.x;       // over 128*2048/4
  int r = (i * 4) >> 11;
  f16x4 h = {0, 0, 0, 0};
  if (r < 96) {
    float4 v = ((const float4*)in)[i];
    h = (f16x4){(_Float16)v.x, (_Float16)v.y, (_Float16)v.z, (_Float16)v.w};
  }
  ((f16x4*)out)[i] = h;
}

// ---------------------------------------------------------------------------
// Causal depthwise conv (k=4) + bias + SiLU; writes fp32 (scan) + f16 (x_proj)
// ---------------------------------------------------------------------------
__global__ __launch_bounds__(256) void conv_silu(
    const float* __restrict__ xz,
    const float* __restrict__ conv_w,
    const float* __restrict__ conv_b,
    float* __restrict__ u32, _Float16* __restrict__ u16)
{
  const int idx = blockIdx.x * 256 + threadIdx.x;  // row*DINNER + d
  const int d   = idx & (DINNER - 1);
  const int row = idx >> 11;
  const int l   = row & (SEQLEN - 1);
  float s = conv_b[d];
#pragma unroll
  for (int k = 0; k < 4; ++k) {
    int lt = l + k - 3;
    if (lt >= 0)
      s = fmaf(xz[(size_t)(row + k - 3) * (2 * DINNER) + d], conv_w[d * 4 + k], s);
  }
  float v = s / (1.f + __expf(-s));
  u32[idx] = v;
  u16[idx] = (_Float16)v;
}

// ---------------------------------------------------------------------------
// Selective scan, no per-step shuffles: per step each (c,n) thread writes
// s*C to LDS (n-major, stride 1025 -> conflict-free reduce); chunk-end
// reduction over n + fused +u*D, *silu(z) epilogue; output f16 for out_proj.
// Critical path per step = one fmaf.
// ---------------------------------------------------------------------------
__global__ __launch_bounds__(256) void scan_kernel(
    const float* __restrict__ delta,   // [MROWS, DINNER]
    const float* __restrict__ u,       // [MROWS, DINNER] fp32
    const float* __restrict__ xz,      // z = xz[:, DINNER:]
    const float* __restrict__ x_dbl,   // [MROWS, 128]; B at 64..79, C at 80..95
    const float* __restrict__ A_log,   // [DINNER, 16]
    const float* __restrict__ Dp,      // [DINNER]
    _Float16* __restrict__ y16)        // [MROWS, DINNER] f16
{
  const int t = threadIdx.x;
  const int c = t >> 4;          // chain 0..15
  const int n = t & 15;          // state 0..15
  const int bb = blockIdx.x;
  const int b = bb >> 7;
  const int d_base = (bb & 127) * 16;

  const float A_dn = -__expf(A_log[(d_base + c) * DSTATE + n]);
  float s = 0.f;

  __shared__ __align__(16) float delta_s[64 * 16];
  __shared__ __align__(16) float u_s[64 * 16];
  __shared__ __align__(16) float z_s[64 * 16];
  __shared__ __align__(16) float B_s[64 * 16];
  __shared__ __align__(16) float C_s[64 * 16];
  __shared__ float y_part[16 * 1025];   // [n][o=i*16+c], stride 1025
  __shared__ float Dp_s[16];

  if (t < 16) Dp_s[t] = Dp[d_base + t];

  const int j0 = t * 4;
  const int i_st = t >> 2;       // staging step 0..63
  const int cc = (t & 3) * 4;

  for (int l0 = 0; l0 < SEQLEN; l0 += 64) {
    const int row = b * SEQLEN + l0 + i_st;
    *(float4*)&delta_s[j0] = *(const float4*)&delta[(size_t)row * DINNER + d_base + cc];
    *(float4*)&u_s[j0]     = *(const float4*)&u[(size_t)row * DINNER + d_base + cc];
    *(float4*)&z_s[j0]     = *(const float4*)&xz[(size_t)row * (2 * DINNER) + DINNER + d_base + cc];
    *(float4*)&B_s[j0]     = *(const float4*)&x_dbl[(size_t)row * XPAD + DTRANK + cc];
    *(float4*)&C_s[j0]     = *(const float4*)&x_dbl[(size_t)row * XPAD + DTRANK + DSTATE + cc];
    __syncthreads();

#pragma unroll 8
    for (int i = 0; i < 64; ++i) {
      float dv = delta_s[i * 16 + c];
      float uv = u_s[i * 16 + c];
      float Bv = B_s[i * 16 + n];
      float Cv = C_s[i * 16 + n];
      float dA = __expf(dv * A_dn);
      s = fmaf(dA, s, dv * Bv * uv);
      y_part[n * 1025 + i * 16 + c] = s * Cv;
    }
    __syncthreads();

    // reduce over n; o = t + 256k covers (i = o>>4, chain = o&15)
#pragma unroll
    for (int k = 0; k < 4; ++k) {
      int o = t + 256 * k;
      float ssum = 0.f;
#pragma unroll
      for (int n2 = 0; n2 < 16; ++n2) ssum += y_part[n2 * 1025 + o];
      int i = o >> 4, c2 = o & 15;
      float uv = u_s[o];
      float zv = z_s[o];
      float yv = fmaf(uv, Dp_s[c2], ssum);
      yv *= zv / (1.f + __expf(-zv));
      y16[(size_t)(b * SEQLEN + l0 + i) * DINNER + d_base + c2] = (_Float16)yv;
    }
    __syncthreads();
  }
}

// ---------------------------------------------------------------------------
extern "C" void kernel_launch(void* const* d_in, const int* in_sizes, int n_in,
                              void* d_out, int out_size, void* d_ws, size_t ws_size,
                              hipStream_t stream)
{
  const float* hidden     = (const float*)d_in[0];
  const float* in_proj_w  = (const float*)d_in[1];
  const float* conv_w     = (const float*)d_in[2];
  const float* conv_b     = (const float*)d_in[3];
  const float* x_proj_w   = (const float*)d_in[4];
  const float* dt_proj_w  = (const float*)d_in[5];
  const float* dt_proj_b  = (const float*)d_in[6];
  const float* A_log      = (const float*)d_in[7];
  const float* Dp         = (const float*)d_in[8];
  const float* out_proj_w = (const float*)d_in[9];
  float* out = (float*)d_out;

  char* p = (char*)d_ws;
  float*    xz     = (float*)p;     p += (size_t)MROWS * 2 * DINNER * 4;  // 33.6MB
  float*    u32    = (float*)p;     p += (size_t)MROWS * DINNER * 4;      // 16.8MB
  float*    xdbl32 = (float*)p;     p += (size_t)MROWS * XPAD * 4;        // 1.05MB
  float*    delta  = (float*)p;     p += (size_t)MROWS * DINNER * 4;      // 16.8MB
  _Float16* h16    = (_Float16*)p;  p += (size_t)MROWS * DMODEL * 2;      // hidden f16
  _Float16* win16  = (_Float16*)p;  p += (size_t)2 * DINNER * DMODEL * 2;
  _Float16* wout16 = (_Float16*)p;  p += (size_t)DMODEL * DINNER * 2;
  _Float16* wdt16  = (_Float16*)p;  p += (size_t)DINNER * DTRANK * 2;
  _Float16* wxp16  = (_Float16*)p;  p += (size_t)XPAD * DINNER * 2;
  _Float16* u16    = (_Float16*)p;  p += (size_t)MROWS * DINNER * 2;
  _Float16* xdbl16 = (_Float16*)p;  p += (size_t)MROWS * DTRANK * 2;
  _Float16* y16    = (_Float16*)p;  p += (size_t)MROWS * DINNER * 2;

  // 0. fp16 conversions (weights + hidden); activations fused into producers
  f2h<<<(MROWS * DMODEL / 4 + 255) / 256, 256, 0, stream>>>(hidden, h16, MROWS * DMODEL / 4);
  f2h<<<(2 * DINNER * DMODEL / 4 + 255) / 256, 256, 0, stream>>>(in_proj_w, win16, 2 * DINNER * DMODEL / 4);
  f2h<<<(DMODEL * DINNER / 4 + 255) / 256, 256, 0, stream>>>(out_proj_w, wout16, DMODEL * DINNER / 4);
  f2h<<<(DINNER * DTRANK / 4 + 255) / 256, 256, 0, stream>>>(dt_proj_w, wdt16, DINNER * DTRANK / 4);
  f2h_pad<<<(XPAD * DINNER / 4) / 256, 256, 0, stream>>>(x_proj_w, wxp16);

  // 1. in_proj: xz = hidden @ in_proj_w^T   [2048, 4096], K=1024
  hgemm<0><<<dim3(2 * DINNER / 128, MROWS / 128, 1), 256, 0, stream>>>(
      h16, DMODEL, win16, DMODEL, xz, 2 * DINNER, DMODEL, nullptr, nullptr);

  // 2. conv + SiLU -> u32, u16
  conv_silu<<<(MROWS * DINNER) / 256, 256, 0, stream>>>(xz, conv_w, conv_b, u32, u16);

  // 3. x_proj: x_dbl = u @ x_proj_w^T  [2048, 128pad], K=2048; f16 copy of dt cols
  hgemm<3><<<dim3(1, MROWS / 128, 1), 256, 0, stream>>>(
      u16, DINNER, wxp16, DINNER, xdbl32, XPAD, DINNER, nullptr, xdbl16);

  // 4. dt: delta = softplus(x_dbl[:, :64] @ dt_proj_w^T + 2*b)  [2048,2048], K=64
  hgemm<2><<<dim3(DINNER / 128, MROWS / 128, 1), 256, 0, stream>>>(
      xdbl16, DTRANK, wdt16, DTRANK, delta, DINNER, DTRANK, dt_proj_b, nullptr);

  // 5. selective scan -> y16 (fused +u*D, *silu(z))
  scan_kernel<<<256, 256, 0, stream>>>(delta, u32, xz, xdbl32, A_log, Dp, y16);

  // 6. out_proj: out = y @ out_proj_w^T [2048, 1024], K=2048, split-K=2
  hipMemsetAsync(out, 0, (size_t)MROWS * DMODEL * 4, stream);
  hgemm<1><<<dim3(DMODEL / 128, MROWS / 128, 2), 256, 0, stream>>>(
      y16, DINNER, wout16, DINNER, out, DMODEL, DINNER, nullptr, nullptr);
}

// Round 3
// 320.281 us; speedup vs baseline: 2.4709x; 1.1655x over previous
//
#include <hip/hip_runtime.h>
#include <hip/hip_bf16.h>
#include <math.h>

#define BATCH   2
#define SEQLEN  1024
#define DMODEL  1024
#define DINNER  2048
#define DSTATE  16
#define DTRANK  64
#define XPAD    128             // padded x_dbl row stride (96 -> 128)
#define MROWS   (BATCH*SEQLEN)  // 2048

typedef float    f32x4  __attribute__((ext_vector_type(4)));
typedef _Float16 f16x8  __attribute__((ext_vector_type(8)));
typedef _Float16 f16x4  __attribute__((ext_vector_type(4)));

#define GLD_LDS(g, l) \
  __builtin_amdgcn_global_load_lds((const __attribute__((address_space(1))) void*)(g), \
                                   (__attribute__((address_space(3))) void*)(l), 16, 0, 0)

// ---------------------------------------------------------------------------
// fp16 MFMA GEMM: C[M,N](fp32) = A[M,K](f16) @ W[N,K](f16)^T
// 128x128 tile, 256 thr (4 waves 2x2), BK=32, 16x16x32 MFMA, 4x4 tiles/wave.
// EPI 0: plain fp32 store   1: atomicAdd (split-K)   2: softplus(acc+2*bias)
// ---------------------------------------------------------------------------
template<int EPI>
__global__ __launch_bounds__(256) void hgemm(
    const _Float16* __restrict__ A, int lda,
    const _Float16* __restrict__ W, int ldw,
    float* __restrict__ C, int ldc, int K,
    const float* __restrict__ bias)
{
  __shared__ _Float16 As[4096];   // 4 kb * 128 rows * 8 halves
  __shared__ _Float16 Bs[4096];

  const int t  = threadIdx.x;
  const int m0 = blockIdx.y * 128, n0 = blockIdx.x * 128;
  const int kchunk = K / gridDim.z;
  const int kbeg = blockIdx.z * kchunk;

  const _Float16* gA = A + (size_t)(m0 + (t & 127)) * lda + kbeg + (t >> 7) * 8;
  const _Float16* gB = W + (size_t)(n0 + (t & 127)) * ldw + kbeg + (t >> 7) * 8;
  _Float16* lA = As + t * 8;
  _Float16* lB = Bs + t * 8;

  const int lane = t & 63, wvi = t >> 6;
  const int wm = (wvi >> 1) * 64, wn = (wvi & 1) * 64;
  const int lm = lane & 15, lk = lane >> 4;

  f32x4 acc[4][4] = {};

  for (int kk = 0; kk < kchunk; kk += 32) {
    GLD_LDS(gA,      lA);
    GLD_LDS(gA + 16, lA + 2048);
    GLD_LDS(gB,      lB);
    GLD_LDS(gB + 16, lB + 2048);
    gA += 32; gB += 32;
    __syncthreads();

    f16x8 av[4], bv[4];
#pragma unroll
    for (int i = 0; i < 4; ++i)
      av[i] = *(const f16x8*)&As[lk * 1024 + (wm + i * 16 + lm) * 8];
#pragma unroll
    for (int j = 0; j < 4; ++j)
      bv[j] = *(const f16x8*)&Bs[lk * 1024 + (wn + j * 16 + lm) * 8];
#pragma unroll
    for (int i = 0; i < 4; ++i)
#pragma unroll
      for (int j = 0; j < 4; ++j)
        acc[i][j] = __builtin_amdgcn_mfma_f32_16x16x32_f16(av[i], bv[j], acc[i][j], 0, 0, 0);
    __syncthreads();
  }

  // epilogue: C/D layout col=lane&15, row=(lane>>4)*4+reg
#pragma unroll
  for (int i = 0; i < 4; ++i) {
    const int mrow = m0 + wm + i * 16 + lk * 4;
#pragma unroll
    for (int j = 0; j < 4; ++j) {
      const int col = n0 + wn + j * 16 + lm;
#pragma unroll
      for (int r = 0; r < 4; ++r) {
        float v = acc[i][j][r];
        size_t off = (size_t)(mrow + r) * ldc + col;
        if constexpr (EPI == 0) {
          C[off] = v;
        } else if constexpr (EPI == 1) {
          atomicAdd(&C[off], v);
        } else {  // EPI == 2
          float x = v + 2.f * bias[col];
          C[off] = (x > 20.f) ? x : log1pf(__expf(x));
        }
      }
    }
  }
}

// ---------------------------------------------------------------------------
// Fused fp32 -> fp16 conversion of all weights + hidden (one launch).
// Unit = one float4. Region order: hidden, in_proj_w, out_proj_w, dt_proj_w,
// x_proj_w (padded 96->128 rows with zeros).
// ---------------------------------------------------------------------------
#define R0 (MROWS * DMODEL / 4)            // hidden:      524288
#define R1 (2 * DINNER * DMODEL / 4)       // in_proj_w:  1048576
#define R2 (DMODEL * DINNER / 4)           // out_proj_w:  524288
#define R3 (DINNER * DTRANK / 4)           // dt_proj_w:    32768
#define R4 (XPAD * DINNER / 4)             // x_proj_w pad: 65536
#define F2H_TOTAL (R0 + R1 + R2 + R3 + R4)

__global__ __launch_bounds__(256) void f2h_all(
    const float* __restrict__ hid, const float* __restrict__ w_in,
    const float* __restrict__ w_out, const float* __restrict__ w_dt,
    const float* __restrict__ w_xp,
    _Float16* __restrict__ hid16, _Float16* __restrict__ w_in16,
    _Float16* __restrict__ w_out16, _Float16* __restrict__ w_dt16,
    _Float16* __restrict__ w_xp16)
{
  int i = blockIdx.x * 256 + threadIdx.x;
  const float* src; _Float16* dst; int off;
  if (i < R0)                     { src = hid;   dst = hid16;   off = i; }
  else if (i < R0+R1)             { src = w_in;  dst = w_in16;  off = i - R0; }
  else if (i < R0+R1+R2)          { src = w_out; dst = w_out16; off = i - (R0+R1); }
  else if (i < R0+R1+R2+R3)       { src = w_dt;  dst = w_dt16;  off = i - (R0+R1+R2); }
  else if (i < F2H_TOTAL) {
    off = i - (R0+R1+R2+R3);
    int r = (off * 4) >> 11;                 // row of padded [128, 2048]
    f16x4 h = {0, 0, 0, 0};
    if (r < 96) {
      float4 v = ((const float4*)w_xp)[off];
      h = (f16x4){(_Float16)v.x, (_Float16)v.y, (_Float16)v.z, (_Float16)v.w};
    }
    ((f16x4*)w_xp16)[off] = h;
    return;
  } else return;
  float4 v = ((const float4*)src)[off];
  ((f16x4*)dst)[off] = (f16x4){(_Float16)v.x, (_Float16)v.y, (_Float16)v.z, (_Float16)v.w};
}

// xdbl32[:, 0:64] -> f16 [2048, 64] (dt GEMM input)
__global__ __launch_bounds__(256) void cvt_dt(const float* __restrict__ in,
                                              _Float16* __restrict__ out)
{
  int i = blockIdx.x * 256 + threadIdx.x;        // over 2048*64/4
  int row = i >> 4, col = (i & 15) * 4;
  float4 v = *(const float4*)&in[row * XPAD + col];
  *(f16x4*)&out[row * DTRANK + col] =
      (f16x4){(_Float16)v.x, (_Float16)v.y, (_Float16)v.z, (_Float16)v.w};
}

// ---------------------------------------------------------------------------
// Causal depthwise conv (k=4) + bias + SiLU; writes fp32 (scan) + f16 (x_proj)
// ---------------------------------------------------------------------------
__global__ __launch_bounds__(256) void conv_silu(
    const float* __restrict__ xz,
    const float* __restrict__ conv_w,
    const float* __restrict__ conv_b,
    float* __restrict__ u32, _Float16* __restrict__ u16)
{
  const int idx = blockIdx.x * 256 + threadIdx.x;  // row*DINNER + d
  const int d   = idx & (DINNER - 1);
  const int row = idx >> 11;
  const int l   = row & (SEQLEN - 1);
  float s = conv_b[d];
#pragma unroll
  for (int k = 0; k < 4; ++k) {
    int lt = l + k - 3;
    if (lt >= 0)
      s = fmaf(xz[(size_t)(row + k - 3) * (2 * DINNER) + d], conv_w[d * 4 + k], s);
  }
  float v = s / (1.f + __expf(-s));
  u32[idx] = v;
  u16[idx] = (_Float16)v;
}

// ---------------------------------------------------------------------------
// Selective scan v3: DPP n-reduction (no LDS on the per-step path except
// b128 operand reads), transposed [c|n][i] LDS staging (stride 68 -> all
// accesses <=2-way bank aliased = free), 4-step register batching.
// Block = 256 thr = 16 chains x 16 states; chain c occupies one DPP row.
// ---------------------------------------------------------------------------
__device__ __forceinline__ float row_sum16(float x) {
  int v = __builtin_bit_cast(int, x);
  x += __builtin_bit_cast(float, __builtin_amdgcn_update_dpp(0, v, 0x128, 0xF, 0xF, true)); // row_ror:8
  v = __builtin_bit_cast(int, x);
  x += __builtin_bit_cast(float, __builtin_amdgcn_update_dpp(0, v, 0x124, 0xF, 0xF, true)); // row_ror:4
  v = __builtin_bit_cast(int, x);
  x += __builtin_bit_cast(float, __builtin_amdgcn_update_dpp(0, v, 0x4E, 0xF, 0xF, true));  // quad xor2
  v = __builtin_bit_cast(int, x);
  x += __builtin_bit_cast(float, __builtin_amdgcn_update_dpp(0, v, 0xB1, 0xF, 0xF, true));  // quad xor1
  return x;
}

__global__ __launch_bounds__(256) void scan_kernel(
    const float* __restrict__ delta,   // [MROWS, DINNER]
    const float* __restrict__ u,       // [MROWS, DINNER] fp32
    const float* __restrict__ xz,      // z = xz[:, DINNER:]
    const float* __restrict__ x_dbl,   // [MROWS, 128]; B at 64..79, C at 80..95
    const float* __restrict__ A_log,   // [DINNER, 16]
    const float* __restrict__ Dp,      // [DINNER]
    _Float16* __restrict__ y16)        // [MROWS, DINNER] f16
{
  const int t = threadIdx.x;
  const int c = t >> 4;          // chain 0..15 (DPP row)
  const int n = t & 15;          // state 0..15 (lane within row)
  const int bb = blockIdx.x;
  const int b = bb >> 7;
  const int d_base = (bb & 127) * 16;

  const float A_dn = -__expf(A_log[(d_base + c) * DSTATE + n]);
  float s = 0.f;

  // transposed stride-68 arrays: rows 16B-aligned, reads conflict-free
  __shared__ __align__(16) float dl[16 * 68];
  __shared__ __align__(16) float ul[16 * 68];
  __shared__ __align__(16) float Bl[16 * 68];
  __shared__ __align__(16) float Cl[16 * 68];
  __shared__ __align__(16) float yl[16 * 68];
  __shared__ __align__(16) float z_s[64 * 16];
  __shared__ float Dp_s[16];

  if (t < 16) Dp_s[t] = Dp[d_base + t];

  const int i_st = t >> 2;       // staging step 0..63
  const int cc = (t & 3) * 4;    // staging lane group 0,4,8,12

  for (int l0 = 0; l0 < SEQLEN; l0 += 64) {
    const int row = b * SEQLEN + l0 + i_st;
    {
      float4 dv = *(const float4*)&delta[(size_t)row * DINNER + d_base + cc];
      float4 uv = *(const float4*)&u[(size_t)row * DINNER + d_base + cc];
      float4 Bv = *(const float4*)&x_dbl[(size_t)row * XPAD + DTRANK + cc];
      float4 Cv = *(const float4*)&x_dbl[(size_t)row * XPAD + DTRANK + DSTATE + cc];
      float4 zv = *(const float4*)&xz[(size_t)row * (2 * DINNER) + DINNER + d_base + cc];
      dl[(cc+0)*68 + i_st] = dv.x; dl[(cc+1)*68 + i_st] = dv.y;
      dl[(cc+2)*68 + i_st] = dv.z; dl[(cc+3)*68 + i_st] = dv.w;
      ul[(cc+0)*68 + i_st] = uv.x; ul[(cc+1)*68 + i_st] = uv.y;
      ul[(cc+2)*68 + i_st] = uv.z; ul[(cc+3)*68 + i_st] = uv.w;
      Bl[(cc+0)*68 + i_st] = Bv.x; Bl[(cc+1)*68 + i_st] = Bv.y;
      Bl[(cc+2)*68 + i_st] = Bv.z; Bl[(cc+3)*68 + i_st] = Bv.w;
      Cl[(cc+0)*68 + i_st] = Cv.x; Cl[(cc+1)*68 + i_st] = Cv.y;
      Cl[(cc+2)*68 + i_st] = Cv.z; Cl[(cc+3)*68 + i_st] = Cv.w;
      *(float4*)&z_s[t * 4] = zv;
    }
    __syncthreads();

#pragma unroll
    for (int i0 = 0; i0 < 64; i0 += 4) {
      f32x4 dv4 = *(const f32x4*)&dl[c * 68 + i0];
      f32x4 uv4 = *(const f32x4*)&ul[c * 68 + i0];
      f32x4 Bv4 = *(const f32x4*)&Bl[n * 68 + i0];
      f32x4 Cv4 = *(const f32x4*)&Cl[n * 68 + i0];
      f32x4 py;
#pragma unroll
      for (int r = 0; r < 4; ++r) {
        float dA = __expf(dv4[r] * A_dn);
        s = fmaf(dA, s, dv4[r] * Bv4[r] * uv4[r]);
        py[r] = row_sum16(s * Cv4[r]);   // all lanes get the chain sum
      }
      if (n == 0) *(f32x4*)&yl[c * 68 + i0] = py;
    }
    __syncthreads();

    // epilogue: o = t + 256k enumerates (i = o>>4, chain = o&15)
#pragma unroll
    for (int k = 0; k < 4; ++k) {
      int o = t + 256 * k;
      int i = o >> 4, c2 = o & 15;
      float ssum = yl[c2 * 68 + i];
      float uv = ul[c2 * 68 + i];
      float zv = z_s[o];
      float yv = fmaf(uv, Dp_s[c2], ssum);
      yv *= zv / (1.f + __expf(-zv));
      y16[(size_t)(b * SEQLEN + l0 + i) * DINNER + d_base + c2] = (_Float16)yv;
    }
    __syncthreads();
  }
}

// ---------------------------------------------------------------------------
extern "C" void kernel_launch(void* const* d_in, const int* in_sizes, int n_in,
                              void* d_out, int out_size, void* d_ws, size_t ws_size,
                              hipStream_t stream)
{
  const float* hidden     = (const float*)d_in[0];
  const float* in_proj_w  = (const float*)d_in[1];
  const float* conv_w     = (const float*)d_in[2];
  const float* conv_b     = (const float*)d_in[3];
  const float* x_proj_w   = (const float*)d_in[4];
  const float* dt_proj_w  = (const float*)d_in[5];
  const float* dt_proj_b  = (const float*)d_in[6];
  const float* A_log      = (const float*)d_in[7];
  const float* Dp         = (const float*)d_in[8];
  const float* out_proj_w = (const float*)d_in[9];
  float* out = (float*)d_out;

  char* p = (char*)d_ws;
  float*    xz     = (float*)p;     p += (size_t)MROWS * 2 * DINNER * 4;
  float*    u32    = (float*)p;     p += (size_t)MROWS * DINNER * 4;
  float*    xdbl32 = (float*)p;     p += (size_t)MROWS * XPAD * 4;
  float*    delta  = (float*)p;     p += (size_t)MROWS * DINNER * 4;
  _Float16* h16    = (_Float16*)p;  p += (size_t)MROWS * DMODEL * 2;
  _Float16* win16  = (_Float16*)p;  p += (size_t)2 * DINNER * DMODEL * 2;
  _Float16* wout16 = (_Float16*)p;  p += (size_t)DMODEL * DINNER * 2;
  _Float16* wdt16  = (_Float16*)p;  p += (size_t)DINNER * DTRANK * 2;
  _Float16* wxp16  = (_Float16*)p;  p += (size_t)XPAD * DINNER * 2;
  _Float16* u16    = (_Float16*)p;  p += (size_t)MROWS * DINNER * 2;
  _Float16* xdbl16 = (_Float16*)p;  p += (size_t)MROWS * DTRANK * 2;
  _Float16* y16    = (_Float16*)p;  p += (size_t)MROWS * DINNER * 2;

  // 0. all fp32->fp16 conversions in one launch
  f2h_all<<<(F2H_TOTAL + 255) / 256, 256, 0, stream>>>(
      hidden, in_proj_w, out_proj_w, dt_proj_w, x_proj_w,
      h16, win16, wout16, wdt16, wxp16);

  // 1. in_proj: xz = hidden @ in_proj_w^T   [2048, 4096], K=1024
  hgemm<0><<<dim3(2 * DINNER / 128, MROWS / 128, 1), 256, 0, stream>>>(
      h16, DMODEL, win16, DMODEL, xz, 2 * DINNER, DMODEL, nullptr);

  // 2. conv + SiLU -> u32, u16
  conv_silu<<<(MROWS * DINNER) / 256, 256, 0, stream>>>(xz, conv_w, conv_b, u32, u16);

  // 3. x_proj: x_dbl = u @ x_proj_w^T  [2048, 128pad], K=2048, split-K=8
  hipMemsetAsync(xdbl32, 0, (size_t)MROWS * XPAD * 4, stream);
  hgemm<1><<<dim3(1, MROWS / 128, 8), 256, 0, stream>>>(
      u16, DINNER, wxp16, DINNER, xdbl32, XPAD, DINNER, nullptr);

  // 3b. f16 copy of dt cols
  cvt_dt<<<(MROWS * DTRANK / 4) / 256, 256, 0, stream>>>(xdbl32, xdbl16);

  // 4. dt: delta = softplus(x_dbl[:, :64] @ dt_proj_w^T + 2*b)  [2048,2048], K=64
  hgemm<2><<<dim3(DINNER / 128, MROWS / 128, 1), 256, 0, stream>>>(
      xdbl16, DTRANK, wdt16, DTRANK, delta, DINNER, DTRANK, dt_proj_b);

  // 5. selective scan -> y16 (fused +u*D, *silu(z))
  scan_kernel<<<256, 256, 0, stream>>>(delta, u32, xz, xdbl32, A_log, Dp, y16);

  // 6. out_proj: out = y @ out_proj_w^T [2048, 1024], K=2048, split-K=2
  hipMemsetAsync(out, 0, (size_t)MROWS * DMODEL * 4, stream);
  hgemm<1><<<dim3(DMODEL / 128, MROWS / 128, 2), 256, 0, stream>>>(
      y16, DINNER, wout16, DINNER, out, DMODEL, DINNER, nullptr);
}

// Round 4
// 302.737 us; speedup vs baseline: 2.6141x; 1.0580x over previous
//
#include <hip/hip_runtime.h>
#include <hip/hip_bf16.h>
#include <math.h>

#define BATCH   2
#define SEQLEN  1024
#define DMODEL  1024
#define DINNER  2048
#define DSTATE  16
#define DTRANK  64
#define XPAD    128             // padded x_dbl row stride (96 -> 128)
#define MROWS   (BATCH*SEQLEN)  // 2048
#define NSEG    8
#define SEGLEN  (SEQLEN/NSEG)   // 128

typedef float    f32x4  __attribute__((ext_vector_type(4)));
typedef _Float16 f16x8  __attribute__((ext_vector_type(8)));
typedef _Float16 f16x4  __attribute__((ext_vector_type(4)));

#define GLD_LDS(g, l) \
  __builtin_amdgcn_global_load_lds((const __attribute__((address_space(1))) void*)(g), \
                                   (__attribute__((address_space(3))) void*)(l), 16, 0, 0)

// ---------------------------------------------------------------------------
// fp16 MFMA GEMM: C[M,N](fp32) = A[M,K](f16) @ W[N,K](f16)^T
// 128x128 tile, 256 thr (4 waves 2x2), BK=32, 16x16x32 MFMA, 4x4 tiles/wave.
// EPI 0: plain fp32 store   1: atomicAdd (split-K)   2: softplus(acc+2*bias)
// ---------------------------------------------------------------------------
template<int EPI>
__global__ __launch_bounds__(256) void hgemm(
    const _Float16* __restrict__ A, int lda,
    const _Float16* __restrict__ W, int ldw,
    float* __restrict__ C, int ldc, int K,
    const float* __restrict__ bias)
{
  __shared__ _Float16 As[4096];   // 4 kb * 128 rows * 8 halves
  __shared__ _Float16 Bs[4096];

  const int t  = threadIdx.x;
  const int m0 = blockIdx.y * 128, n0 = blockIdx.x * 128;
  const int kchunk = K / gridDim.z;
  const int kbeg = blockIdx.z * kchunk;

  const _Float16* gA = A + (size_t)(m0 + (t & 127)) * lda + kbeg + (t >> 7) * 8;
  const _Float16* gB = W + (size_t)(n0 + (t & 127)) * ldw + kbeg + (t >> 7) * 8;
  _Float16* lA = As + t * 8;
  _Float16* lB = Bs + t * 8;

  const int lane = t & 63, wvi = t >> 6;
  const int wm = (wvi >> 1) * 64, wn = (wvi & 1) * 64;
  const int lm = lane & 15, lk = lane >> 4;

  f32x4 acc[4][4] = {};

  for (int kk = 0; kk < kchunk; kk += 32) {
    GLD_LDS(gA,      lA);
    GLD_LDS(gA + 16, lA + 2048);
    GLD_LDS(gB,      lB);
    GLD_LDS(gB + 16, lB + 2048);
    gA += 32; gB += 32;
    __syncthreads();

    f16x8 av[4], bv[4];
#pragma unroll
    for (int i = 0; i < 4; ++i)
      av[i] = *(const f16x8*)&As[lk * 1024 + (wm + i * 16 + lm) * 8];
#pragma unroll
    for (int j = 0; j < 4; ++j)
      bv[j] = *(const f16x8*)&Bs[lk * 1024 + (wn + j * 16 + lm) * 8];
#pragma unroll
    for (int i = 0; i < 4; ++i)
#pragma unroll
      for (int j = 0; j < 4; ++j)
        acc[i][j] = __builtin_amdgcn_mfma_f32_16x16x32_f16(av[i], bv[j], acc[i][j], 0, 0, 0);
    __syncthreads();
  }

  // epilogue: C/D layout col=lane&15, row=(lane>>4)*4+reg
#pragma unroll
  for (int i = 0; i < 4; ++i) {
    const int mrow = m0 + wm + i * 16 + lk * 4;
#pragma unroll
    for (int j = 0; j < 4; ++j) {
      const int col = n0 + wn + j * 16 + lm;
#pragma unroll
      for (int r = 0; r < 4; ++r) {
        float v = acc[i][j][r];
        size_t off = (size_t)(mrow + r) * ldc + col;
        if constexpr (EPI == 0) {
          C[off] = v;
        } else if constexpr (EPI == 1) {
          atomicAdd(&C[off], v);
        } else {  // EPI == 2
          float x = v + 2.f * bias[col];
          C[off] = (x > 20.f) ? x : log1pf(__expf(x));
        }
      }
    }
  }
}

// ---------------------------------------------------------------------------
// Fused fp32 -> fp16 conversion of all weights + hidden (one launch).
// ---------------------------------------------------------------------------
#define R0 (MROWS * DMODEL / 4)            // hidden:      524288
#define R1 (2 * DINNER * DMODEL / 4)       // in_proj_w:  1048576
#define R2 (DMODEL * DINNER / 4)           // out_proj_w:  524288
#define R3 (DINNER * DTRANK / 4)           // dt_proj_w:    32768
#define R4 (XPAD * DINNER / 4)             // x_proj_w pad: 65536
#define F2H_TOTAL (R0 + R1 + R2 + R3 + R4)

__global__ __launch_bounds__(256) void f2h_all(
    const float* __restrict__ hid, const float* __restrict__ w_in,
    const float* __restrict__ w_out, const float* __restrict__ w_dt,
    const float* __restrict__ w_xp,
    _Float16* __restrict__ hid16, _Float16* __restrict__ w_in16,
    _Float16* __restrict__ w_out16, _Float16* __restrict__ w_dt16,
    _Float16* __restrict__ w_xp16)
{
  int i = blockIdx.x * 256 + threadIdx.x;
  const float* src; _Float16* dst; int off;
  if (i < R0)                     { src = hid;   dst = hid16;   off = i; }
  else if (i < R0+R1)             { src = w_in;  dst = w_in16;  off = i - R0; }
  else if (i < R0+R1+R2)          { src = w_out; dst = w_out16; off = i - (R0+R1); }
  else if (i < R0+R1+R2+R3)       { src = w_dt;  dst = w_dt16;  off = i - (R0+R1+R2); }
  else if (i < F2H_TOTAL) {
    off = i - (R0+R1+R2+R3);
    int r = (off * 4) >> 11;                 // row of padded [128, 2048]
    f16x4 h = {0, 0, 0, 0};
    if (r < 96) {
      float4 v = ((const float4*)w_xp)[off];
      h = (f16x4){(_Float16)v.x, (_Float16)v.y, (_Float16)v.z, (_Float16)v.w};
    }
    ((f16x4*)w_xp16)[off] = h;
    return;
  } else return;
  float4 v = ((const float4*)src)[off];
  ((f16x4*)dst)[off] = (f16x4){(_Float16)v.x, (_Float16)v.y, (_Float16)v.z, (_Float16)v.w};
}

// xdbl32[:, 0:64] -> f16 [2048, 64] (dt GEMM input)
__global__ __launch_bounds__(256) void cvt_dt(const float* __restrict__ in,
                                              _Float16* __restrict__ out)
{
  int i = blockIdx.x * 256 + threadIdx.x;        // over 2048*64/4
  int row = i >> 4, col = (i & 15) * 4;
  float4 v = *(const float4*)&in[row * XPAD + col];
  *(f16x4*)&out[row * DTRANK + col] =
      (f16x4){(_Float16)v.x, (_Float16)v.y, (_Float16)v.z, (_Float16)v.w};
}

// ---------------------------------------------------------------------------
// Causal depthwise conv (k=4) + bias + SiLU; writes fp32 (scan) + f16 (x_proj)
// ---------------------------------------------------------------------------
__global__ __launch_bounds__(256) void conv_silu(
    const float* __restrict__ xz,
    const float* __restrict__ conv_w,
    const float* __restrict__ conv_b,
    float* __restrict__ u32, _Float16* __restrict__ u16)
{
  const int idx = blockIdx.x * 256 + threadIdx.x;  // row*DINNER + d
  const int d   = idx & (DINNER - 1);
  const int row = idx >> 11;
  const int l   = row & (SEQLEN - 1);
  float s = conv_b[d];
#pragma unroll
  for (int k = 0; k < 4; ++k) {
    int lt = l + k - 3;
    if (lt >= 0)
      s = fmaf(xz[(size_t)(row + k - 3) * (2 * DINNER) + d], conv_w[d * 4 + k], s);
  }
  float v = s / (1.f + __expf(-s));
  u32[idx] = v;
  u16[idx] = (_Float16)v;
}

// ---------------------------------------------------------------------------
// Selective scan, two-pass sequence-split. The recurrence s_t = a_t s + b_t
// over a segment is linear: s_out = P*s_in + E with P = prod a, E = local
// scan from zero. part1 computes (P, E) per (b, d-group, seg) chain at 8x
// block parallelism; part2 combines prefixes in-register and runs the full
// scan + DPP n-reduction + gated epilogue for its 128-step segment.
// Block = 256 thr = 16 chains x 16 states; grid = 2048 (b x 128 dgrp x 8 seg).
// ---------------------------------------------------------------------------
__device__ __forceinline__ float row_sum16(float x) {
  int v = __builtin_bit_cast(int, x);
  x += __builtin_bit_cast(float, __builtin_amdgcn_update_dpp(0, v, 0x128, 0xF, 0xF, true)); // row_ror:8
  v = __builtin_bit_cast(int, x);
  x += __builtin_bit_cast(float, __builtin_amdgcn_update_dpp(0, v, 0x124, 0xF, 0xF, true)); // row_ror:4
  v = __builtin_bit_cast(int, x);
  x += __builtin_bit_cast(float, __builtin_amdgcn_update_dpp(0, v, 0x4E, 0xF, 0xF, true));  // quad xor2
  v = __builtin_bit_cast(int, x);
  x += __builtin_bit_cast(float, __builtin_amdgcn_update_dpp(0, v, 0xB1, 0xF, 0xF, true));  // quad xor1
  return x;
}

__global__ __launch_bounds__(256) void scan_part1(
    const float* __restrict__ delta,   // [MROWS, DINNER]
    const float* __restrict__ u,       // [MROWS, DINNER]
    const float* __restrict__ x_dbl,   // [MROWS, 128]; B at 64..79
    const float* __restrict__ A_log,   // [DINNER, 16]
    float* __restrict__ pbuf,          // [256 grp][8 seg][256 t]
    float* __restrict__ ebuf)
{
  const int t = threadIdx.x;
  const int c = t >> 4, n = t & 15;
  const int bb = blockIdx.x;
  const int seg = bb >> 8;
  const int r = bb & 255;              // b*128 + dgroup
  const int b = r >> 7;
  const int d_base = (r & 127) * 16;

  const float A_dn = -__expf(A_log[(d_base + c) * DSTATE + n]);
  float s = 0.f, p = 1.f;

  __shared__ __align__(16) float dl[16 * 68];
  __shared__ __align__(16) float ul[16 * 68];
  __shared__ __align__(16) float Bl[16 * 68];

  const int i_st = t >> 2;
  const int cc = (t & 3) * 4;

  for (int l0 = seg * SEGLEN; l0 < seg * SEGLEN + SEGLEN; l0 += 64) {
    const int row = b * SEQLEN + l0 + i_st;
    {
      float4 dv = *(const float4*)&delta[(size_t)row * DINNER + d_base + cc];
      float4 uv = *(const float4*)&u[(size_t)row * DINNER + d_base + cc];
      float4 Bv = *(const float4*)&x_dbl[(size_t)row * XPAD + DTRANK + cc];
      dl[(cc+0)*68 + i_st] = dv.x; dl[(cc+1)*68 + i_st] = dv.y;
      dl[(cc+2)*68 + i_st] = dv.z; dl[(cc+3)*68 + i_st] = dv.w;
      ul[(cc+0)*68 + i_st] = uv.x; ul[(cc+1)*68 + i_st] = uv.y;
      ul[(cc+2)*68 + i_st] = uv.z; ul[(cc+3)*68 + i_st] = uv.w;
      Bl[(cc+0)*68 + i_st] = Bv.x; Bl[(cc+1)*68 + i_st] = Bv.y;
      Bl[(cc+2)*68 + i_st] = Bv.z; Bl[(cc+3)*68 + i_st] = Bv.w;
    }
    __syncthreads();
#pragma unroll
    for (int i0 = 0; i0 < 64; i0 += 4) {
      f32x4 dv4 = *(const f32x4*)&dl[c * 68 + i0];
      f32x4 uv4 = *(const f32x4*)&ul[c * 68 + i0];
      f32x4 Bv4 = *(const f32x4*)&Bl[n * 68 + i0];
#pragma unroll
      for (int rr = 0; rr < 4; ++rr) {
        float dA = __expf(dv4[rr] * A_dn);
        s = fmaf(dA, s, dv4[rr] * Bv4[rr] * uv4[rr]);
        p *= dA;
      }
    }
    __syncthreads();
  }
  const int peIdx = (r * NSEG + seg) * 256 + t;
  pbuf[peIdx] = p;
  ebuf[peIdx] = s;
}

__global__ __launch_bounds__(256) void scan_part2(
    const float* __restrict__ delta,
    const float* __restrict__ u,
    const float* __restrict__ xz,      // z = xz[:, DINNER:]
    const float* __restrict__ x_dbl,
    const float* __restrict__ A_log,
    const float* __restrict__ Dp,
    const float* __restrict__ pbuf,
    const float* __restrict__ ebuf,
    _Float16* __restrict__ y16)
{
  const int t = threadIdx.x;
  const int c = t >> 4, n = t & 15;
  const int bb = blockIdx.x;
  const int seg = bb >> 8;
  const int r = bb & 255;
  const int b = r >> 7;
  const int d_base = (r & 127) * 16;

  const float A_dn = -__expf(A_log[(d_base + c) * DSTATE + n]);

  // combine prefix segments: s_in = e_{seg-1} + p_{seg-1}*(... )
  float s = 0.f;
  {
    const int base = r * NSEG * 256 + t;
    for (int k = 0; k < seg; ++k)
      s = fmaf(pbuf[base + k * 256], s, ebuf[base + k * 256]);
  }

  __shared__ __align__(16) float dl[16 * 68];
  __shared__ __align__(16) float ul[16 * 68];
  __shared__ __align__(16) float Bl[16 * 68];
  __shared__ __align__(16) float Cl[16 * 68];
  __shared__ __align__(16) float yl[16 * 68];
  __shared__ __align__(16) float z_s[64 * 16];
  __shared__ float Dp_s[16];

  if (t < 16) Dp_s[t] = Dp[d_base + t];

  const int i_st = t >> 2;
  const int cc = (t & 3) * 4;

  for (int l0 = seg * SEGLEN; l0 < seg * SEGLEN + SEGLEN; l0 += 64) {
    const int row = b * SEQLEN + l0 + i_st;
    {
      float4 dv = *(const float4*)&delta[(size_t)row * DINNER + d_base + cc];
      float4 uv = *(const float4*)&u[(size_t)row * DINNER + d_base + cc];
      float4 Bv = *(const float4*)&x_dbl[(size_t)row * XPAD + DTRANK + cc];
      float4 Cv = *(const float4*)&x_dbl[(size_t)row * XPAD + DTRANK + DSTATE + cc];
      float4 zv = *(const float4*)&xz[(size_t)row * (2 * DINNER) + DINNER + d_base + cc];
      dl[(cc+0)*68 + i_st] = dv.x; dl[(cc+1)*68 + i_st] = dv.y;
      dl[(cc+2)*68 + i_st] = dv.z; dl[(cc+3)*68 + i_st] = dv.w;
      ul[(cc+0)*68 + i_st] = uv.x; ul[(cc+1)*68 + i_st] = uv.y;
      ul[(cc+2)*68 + i_st] = uv.z; ul[(cc+3)*68 + i_st] = uv.w;
      Bl[(cc+0)*68 + i_st] = Bv.x; Bl[(cc+1)*68 + i_st] = Bv.y;
      Bl[(cc+2)*68 + i_st] = Bv.z; Bl[(cc+3)*68 + i_st] = Bv.w;
      Cl[(cc+0)*68 + i_st] = Cv.x; Cl[(cc+1)*68 + i_st] = Cv.y;
      Cl[(cc+2)*68 + i_st] = Cv.z; Cl[(cc+3)*68 + i_st] = Cv.w;
      *(float4*)&z_s[t * 4] = zv;
    }
    __syncthreads();

#pragma unroll
    for (int i0 = 0; i0 < 64; i0 += 4) {
      f32x4 dv4 = *(const f32x4*)&dl[c * 68 + i0];
      f32x4 uv4 = *(const f32x4*)&ul[c * 68 + i0];
      f32x4 Bv4 = *(const f32x4*)&Bl[n * 68 + i0];
      f32x4 Cv4 = *(const f32x4*)&Cl[n * 68 + i0];
      f32x4 py;
#pragma unroll
      for (int rr = 0; rr < 4; ++rr) {
        float dA = __expf(dv4[rr] * A_dn);
        s = fmaf(dA, s, dv4[rr] * Bv4[rr] * uv4[rr]);
        py[rr] = row_sum16(s * Cv4[rr]);
      }
      if (n == 0) *(f32x4*)&yl[c * 68 + i0] = py;
    }
    __syncthreads();

#pragma unroll
    for (int k = 0; k < 4; ++k) {
      int o = t + 256 * k;
      int i = o >> 4, c2 = o & 15;
      float ssum = yl[c2 * 68 + i];
      float uv = ul[c2 * 68 + i];
      float zv = z_s[o];
      float yv = fmaf(uv, Dp_s[c2], ssum);
      yv *= zv / (1.f + __expf(-zv));
      y16[(size_t)(b * SEQLEN + l0 + i) * DINNER + d_base + c2] = (_Float16)yv;
    }
    __syncthreads();
  }
}

// ---------------------------------------------------------------------------
extern "C" void kernel_launch(void* const* d_in, const int* in_sizes, int n_in,
                              void* d_out, int out_size, void* d_ws, size_t ws_size,
                              hipStream_t stream)
{
  const float* hidden     = (const float*)d_in[0];
  const float* in_proj_w  = (const float*)d_in[1];
  const float* conv_w     = (const float*)d_in[2];
  const float* conv_b     = (const float*)d_in[3];
  const float* x_proj_w   = (const float*)d_in[4];
  const float* dt_proj_w  = (const float*)d_in[5];
  const float* dt_proj_b  = (const float*)d_in[6];
  const float* A_log      = (const float*)d_in[7];
  const float* Dp         = (const float*)d_in[8];
  const float* out_proj_w = (const float*)d_in[9];
  float* out = (float*)d_out;

  char* p = (char*)d_ws;
  float*    xz     = (float*)p;     p += (size_t)MROWS * 2 * DINNER * 4;
  float*    u32    = (float*)p;     p += (size_t)MROWS * DINNER * 4;
  float*    xdbl32 = (float*)p;     p += (size_t)MROWS * XPAD * 4;
  float*    delta  = (float*)p;     p += (size_t)MROWS * DINNER * 4;
  _Float16* h16    = (_Float16*)p;  p += (size_t)MROWS * DMODEL * 2;
  _Float16* win16  = (_Float16*)p;  p += (size_t)2 * DINNER * DMODEL * 2;
  _Float16* wout16 = (_Float16*)p;  p += (size_t)DMODEL * DINNER * 2;
  _Float16* wdt16  = (_Float16*)p;  p += (size_t)DINNER * DTRANK * 2;
  _Float16* wxp16  = (_Float16*)p;  p += (size_t)XPAD * DINNER * 2;
  _Float16* u16    = (_Float16*)p;  p += (size_t)MROWS * DINNER * 2;
  _Float16* xdbl16 = (_Float16*)p;  p += (size_t)MROWS * DTRANK * 2;
  _Float16* y16    = (_Float16*)p;  p += (size_t)MROWS * DINNER * 2;
  float*    pbuf   = (float*)p;     p += (size_t)256 * NSEG * 256 * 4;
  float*    ebuf   = (float*)p;     p += (size_t)256 * NSEG * 256 * 4;

  // 0. all fp32->fp16 conversions in one launch
  f2h_all<<<(F2H_TOTAL + 255) / 256, 256, 0, stream>>>(
      hidden, in_proj_w, out_proj_w, dt_proj_w, x_proj_w,
      h16, win16, wout16, wdt16, wxp16);

  // 1. in_proj: xz = hidden @ in_proj_w^T   [2048, 4096], K=1024
  hgemm<0><<<dim3(2 * DINNER / 128, MROWS / 128, 1), 256, 0, stream>>>(
      h16, DMODEL, win16, DMODEL, xz, 2 * DINNER, DMODEL, nullptr);

  // 2. conv + SiLU -> u32, u16
  conv_silu<<<(MROWS * DINNER) / 256, 256, 0, stream>>>(xz, conv_w, conv_b, u32, u16);

  // 3. x_proj: x_dbl = u @ x_proj_w^T  [2048, 128pad], K=2048, split-K=8
  hipMemsetAsync(xdbl32, 0, (size_t)MROWS * XPAD * 4, stream);
  hgemm<1><<<dim3(1, MROWS / 128, 8), 256, 0, stream>>>(
      u16, DINNER, wxp16, DINNER, xdbl32, XPAD, DINNER, nullptr);

  // 3b. f16 copy of dt cols
  cvt_dt<<<(MROWS * DTRANK / 4) / 256, 256, 0, stream>>>(xdbl32, xdbl16);

  // 4. dt: delta = softplus(x_dbl[:, :64] @ dt_proj_w^T + 2*b)  [2048,2048], K=64
  hgemm<2><<<dim3(DINNER / 128, MROWS / 128, 1), 256, 0, stream>>>(
      xdbl16, DTRANK, wdt16, DTRANK, delta, DINNER, DTRANK, dt_proj_b);

  // 5. selective scan, two-pass sequence-split -> y16
  scan_part1<<<256 * NSEG, 256, 0, stream>>>(delta, u32, xdbl32, A_log, pbuf, ebuf);
  scan_part2<<<256 * NSEG, 256, 0, stream>>>(delta, u32, xz, xdbl32, A_log, Dp,
                                             pbuf, ebuf, y16);

  // 6. out_proj: out = y @ out_proj_w^T [2048, 1024], K=2048, split-K=2
  hipMemsetAsync(out, 0, (size_t)MROWS * DMODEL * 4, stream);
  hgemm<1><<<dim3(DMODEL / 128, MROWS / 128, 2), 256, 0, stream>>>(
      y16, DINNER, wout16, DINNER, out, DMODEL, DINNER, nullptr);
}

// Round 5
// 296.994 us; speedup vs baseline: 2.6647x; 1.0193x over previous
//
#include <hip/hip_runtime.h>
#include <hip/hip_bf16.h>
#include <math.h>

#define BATCH   2
#define SEQLEN  1024
#define DMODEL  1024
#define DINNER  2048
#define DSTATE  16
#define DTRANK  64
#define XPAD    128             // padded x_dbl row stride (96 -> 128)
#define MROWS   (BATCH*SEQLEN)  // 2048
#define NSEG    8
#define SEGLEN  (SEQLEN/NSEG)   // 128
#define XP_SPLIT  16
#define OUT_SPLIT 4

typedef float    f32x4  __attribute__((ext_vector_type(4)));
typedef _Float16 f16x8  __attribute__((ext_vector_type(8)));
typedef _Float16 f16x4  __attribute__((ext_vector_type(4)));

#define GLD_LDS(g, l) \
  __builtin_amdgcn_global_load_lds((const __attribute__((address_space(1))) void*)(g), \
                                   (__attribute__((address_space(3))) void*)(l), 16, 0, 0)

// ---------------------------------------------------------------------------
// fp16 MFMA GEMM, 64x128 tile (occupancy-oriented): C[M,N] += A[M,K] W[N,K]^T
// 256 thr = 4 waves side by side (each 64m x 32n = 4x2 16x16 tiles).
// BK=32; LDS [kb(4)][row][8] halves -> frag ds_read_b128 conflict-free;
// staging = 3 global_load_lds(16B)/thread/iter (lane-linear dest).
// zstride: partial-buffer offset per blockIdx.z (0 = in-place).
// EPI 0: plain store   2: softplus(acc + 2*bias[col])
// ---------------------------------------------------------------------------
template<int EPI>
__global__ __launch_bounds__(256) void hgemm64(
    const _Float16* __restrict__ A, int lda,
    const _Float16* __restrict__ W, int ldw,
    float* __restrict__ C, int ldc, int K,
    const float* __restrict__ bias, size_t zstride)
{
  __shared__ _Float16 As[2048];   // [kb4][row64][8]
  __shared__ _Float16 Bs[4096];   // [kb4][row128][8]

  const int t  = threadIdx.x;
  const int m0 = blockIdx.y * 64, n0 = blockIdx.x * 128;
  const int kchunk = K / gridDim.z;
  const int kbeg = blockIdx.z * kchunk;

  const _Float16* gA = A + (size_t)(m0 + (t & 63)) * lda + kbeg + (t >> 6) * 8;
  const _Float16* gB = W + (size_t)(n0 + (t & 127)) * ldw + kbeg + (t >> 7) * 8;
  _Float16* lA = As + t * 8;
  _Float16* lB = Bs + t * 8;

  const int lane = t & 63, wvi = t >> 6;
  const int wn = wvi * 32;
  const int lm = lane & 15, lk = lane >> 4;

  f32x4 acc[4][2] = {};

  for (int kk = 0; kk < kchunk; kk += 32) {
    GLD_LDS(gA,      lA);
    GLD_LDS(gB,      lB);
    GLD_LDS(gB + 16, lB + 2048);
    gA += 32; gB += 32;
    __syncthreads();

    f16x8 av[4], bv[2];
#pragma unroll
    for (int i = 0; i < 4; ++i)
      av[i] = *(const f16x8*)&As[lk * 512 + (i * 16 + lm) * 8];
#pragma unroll
    for (int j = 0; j < 2; ++j)
      bv[j] = *(const f16x8*)&Bs[lk * 1024 + (wn + j * 16 + lm) * 8];
#pragma unroll
    for (int i = 0; i < 4; ++i)
#pragma unroll
      for (int j = 0; j < 2; ++j)
        acc[i][j] = __builtin_amdgcn_mfma_f32_16x16x32_f16(av[i], bv[j], acc[i][j], 0, 0, 0);
    __syncthreads();
  }

  float* Cz = C + (size_t)blockIdx.z * zstride;
  // C/D layout: col = lane&15, row = (lane>>4)*4 + reg
#pragma unroll
  for (int i = 0; i < 4; ++i) {
    const int mrow = m0 + i * 16 + lk * 4;
#pragma unroll
    for (int j = 0; j < 2; ++j) {
      const int col = n0 + wn + j * 16 + lm;
#pragma unroll
      for (int r = 0; r < 4; ++r) {
        float v = acc[i][j][r];
        size_t off = (size_t)(mrow + r) * ldc + col;
        if constexpr (EPI == 0) {
          Cz[off] = v;
        } else {  // EPI == 2
          float x = v + 2.f * bias[col];
          Cz[off] = (x > 20.f) ? x : log1pf(__expf(x));
        }
      }
    }
  }
}

// ---------------------------------------------------------------------------
// Fused fp32 -> fp16 conversion of all weights + hidden (one launch).
// ---------------------------------------------------------------------------
#define R0 (MROWS * DMODEL / 4)            // hidden:      524288
#define R1 (2 * DINNER * DMODEL / 4)       // in_proj_w:  1048576
#define R2 (DMODEL * DINNER / 4)           // out_proj_w:  524288
#define R3 (DINNER * DTRANK / 4)           // dt_proj_w:    32768
#define R4 (XPAD * DINNER / 4)             // x_proj_w pad: 65536
#define F2H_TOTAL (R0 + R1 + R2 + R3 + R4)

__global__ __launch_bounds__(256) void f2h_all(
    const float* __restrict__ hid, const float* __restrict__ w_in,
    const float* __restrict__ w_out, const float* __restrict__ w_dt,
    const float* __restrict__ w_xp,
    _Float16* __restrict__ hid16, _Float16* __restrict__ w_in16,
    _Float16* __restrict__ w_out16, _Float16* __restrict__ w_dt16,
    _Float16* __restrict__ w_xp16)
{
  int i = blockIdx.x * 256 + threadIdx.x;
  const float* src; _Float16* dst; int off;
  if (i < R0)                     { src = hid;   dst = hid16;   off = i; }
  else if (i < R0+R1)             { src = w_in;  dst = w_in16;  off = i - R0; }
  else if (i < R0+R1+R2)          { src = w_out; dst = w_out16; off = i - (R0+R1); }
  else if (i < R0+R1+R2+R3)       { src = w_dt;  dst = w_dt16;  off = i - (R0+R1+R2); }
  else if (i < F2H_TOTAL) {
    off = i - (R0+R1+R2+R3);
    int r = (off * 4) >> 11;                 // row of padded [128, 2048]
    f16x4 h = {0, 0, 0, 0};
    if (r < 96) {
      float4 v = ((const float4*)w_xp)[off];
      h = (f16x4){(_Float16)v.x, (_Float16)v.y, (_Float16)v.z, (_Float16)v.w};
    }
    ((f16x4*)w_xp16)[off] = h;
    return;
  } else return;
  float4 v = ((const float4*)src)[off];
  ((f16x4*)dst)[off] = (f16x4){(_Float16)v.x, (_Float16)v.y, (_Float16)v.z, (_Float16)v.w};
}

// ---------------------------------------------------------------------------
// Reduce x_proj split-K partials -> xdbl32 [2048,128] + f16 dt-cols [2048,64]
// ---------------------------------------------------------------------------
__global__ __launch_bounds__(256) void reduce_xdbl(
    const float* __restrict__ part,       // [16][2048*128]
    float* __restrict__ xdbl32, _Float16* __restrict__ xdbl16)
{
  int i = blockIdx.x * 256 + threadIdx.x;          // float4 units, < 65536
  f32x4 s = ((const f32x4*)part)[i];
#pragma unroll
  for (int z = 1; z < XP_SPLIT; ++z)
    s += ((const f32x4*)part)[(size_t)z * (MROWS * XPAD / 4) + i];
  ((f32x4*)xdbl32)[i] = s;
  int col4 = (i & 31) * 4;
  if (col4 < DTRANK) {
    int row = i >> 5;
    *(f16x4*)&xdbl16[(size_t)row * DTRANK + col4] =
        (f16x4){(_Float16)s.x, (_Float16)s.y, (_Float16)s.z, (_Float16)s.w};
  }
}

// ---------------------------------------------------------------------------
// Reduce out_proj split-K partials -> out [2048,1024] fp32
// ---------------------------------------------------------------------------
__global__ __launch_bounds__(256) void reduce_out(
    const float* __restrict__ part, float* __restrict__ out)
{
  int i = blockIdx.x * 256 + threadIdx.x;          // float4 units, < 524288
  f32x4 s = ((const f32x4*)part)[i];
#pragma unroll
  for (int z = 1; z < OUT_SPLIT; ++z)
    s += ((const f32x4*)part)[(size_t)z * (MROWS * DMODEL / 4) + i];
  ((f32x4*)out)[i] = s;
}

// ---------------------------------------------------------------------------
// Causal depthwise conv (k=4) + bias + SiLU; writes fp32 (scan) + f16 (x_proj)
// ---------------------------------------------------------------------------
__global__ __launch_bounds__(256) void conv_silu(
    const float* __restrict__ xz,
    const float* __restrict__ conv_w,
    const float* __restrict__ conv_b,
    float* __restrict__ u32, _Float16* __restrict__ u16)
{
  const int idx = blockIdx.x * 256 + threadIdx.x;  // row*DINNER + d
  const int d   = idx & (DINNER - 1);
  const int row = idx >> 11;
  const int l   = row & (SEQLEN - 1);
  float s = conv_b[d];
#pragma unroll
  for (int k = 0; k < 4; ++k) {
    int lt = l + k - 3;
    if (lt >= 0)
      s = fmaf(xz[(size_t)(row + k - 3) * (2 * DINNER) + d], conv_w[d * 4 + k], s);
  }
  float v = s / (1.f + __expf(-s));
  u32[idx] = v;
  u16[idx] = (_Float16)v;
}

// ---------------------------------------------------------------------------
// Selective scan, two-pass sequence-split (round-4 design, unchanged).
// ---------------------------------------------------------------------------
__device__ __forceinline__ float row_sum16(float x) {
  int v = __builtin_bit_cast(int, x);
  x += __builtin_bit_cast(float, __builtin_amdgcn_update_dpp(0, v, 0x128, 0xF, 0xF, true)); // row_ror:8
  v = __builtin_bit_cast(int, x);
  x += __builtin_bit_cast(float, __builtin_amdgcn_update_dpp(0, v, 0x124, 0xF, 0xF, true)); // row_ror:4
  v = __builtin_bit_cast(int, x);
  x += __builtin_bit_cast(float, __builtin_amdgcn_update_dpp(0, v, 0x4E, 0xF, 0xF, true));  // quad xor2
  v = __builtin_bit_cast(int, x);
  x += __builtin_bit_cast(float, __builtin_amdgcn_update_dpp(0, v, 0xB1, 0xF, 0xF, true));  // quad xor1
  return x;
}

__global__ __launch_bounds__(256) void scan_part1(
    const float* __restrict__ delta,
    const float* __restrict__ u,
    const float* __restrict__ x_dbl,
    const float* __restrict__ A_log,
    float* __restrict__ pbuf, float* __restrict__ ebuf)
{
  const int t = threadIdx.x;
  const int c = t >> 4, n = t & 15;
  const int bb = blockIdx.x;
  const int seg = bb >> 8;
  const int r = bb & 255;
  const int b = r >> 7;
  const int d_base = (r & 127) * 16;

  const float A_dn = -__expf(A_log[(d_base + c) * DSTATE + n]);
  float s = 0.f, p = 1.f;

  __shared__ __align__(16) float dl[16 * 68];
  __shared__ __align__(16) float ul[16 * 68];
  __shared__ __align__(16) float Bl[16 * 68];

  const int i_st = t >> 2;
  const int cc = (t & 3) * 4;

  for (int l0 = seg * SEGLEN; l0 < seg * SEGLEN + SEGLEN; l0 += 64) {
    const int row = b * SEQLEN + l0 + i_st;
    {
      float4 dv = *(const float4*)&delta[(size_t)row * DINNER + d_base + cc];
      float4 uv = *(const float4*)&u[(size_t)row * DINNER + d_base + cc];
      float4 Bv = *(const float4*)&x_dbl[(size_t)row * XPAD + DTRANK + cc];
      dl[(cc+0)*68 + i_st] = dv.x; dl[(cc+1)*68 + i_st] = dv.y;
      dl[(cc+2)*68 + i_st] = dv.z; dl[(cc+3)*68 + i_st] = dv.w;
      ul[(cc+0)*68 + i_st] = uv.x; ul[(cc+1)*68 + i_st] = uv.y;
      ul[(cc+2)*68 + i_st] = uv.z; ul[(cc+3)*68 + i_st] = uv.w;
      Bl[(cc+0)*68 + i_st] = Bv.x; Bl[(cc+1)*68 + i_st] = Bv.y;
      Bl[(cc+2)*68 + i_st] = Bv.z; Bl[(cc+3)*68 + i_st] = Bv.w;
    }
    __syncthreads();
#pragma unroll
    for (int i0 = 0; i0 < 64; i0 += 4) {
      f32x4 dv4 = *(const f32x4*)&dl[c * 68 + i0];
      f32x4 uv4 = *(const f32x4*)&ul[c * 68 + i0];
      f32x4 Bv4 = *(const f32x4*)&Bl[n * 68 + i0];
#pragma unroll
      for (int rr = 0; rr < 4; ++rr) {
        float dA = __expf(dv4[rr] * A_dn);
        s = fmaf(dA, s, dv4[rr] * Bv4[rr] * uv4[rr]);
        p *= dA;
      }
    }
    __syncthreads();
  }
  const int peIdx = (r * NSEG + seg) * 256 + t;
  pbuf[peIdx] = p;
  ebuf[peIdx] = s;
}

__global__ __launch_bounds__(256) void scan_part2(
    const float* __restrict__ delta,
    const float* __restrict__ u,
    const float* __restrict__ xz,
    const float* __restrict__ x_dbl,
    const float* __restrict__ A_log,
    const float* __restrict__ Dp,
    const float* __restrict__ pbuf,
    const float* __restrict__ ebuf,
    _Float16* __restrict__ y16)
{
  const int t = threadIdx.x;
  const int c = t >> 4, n = t & 15;
  const int bb = blockIdx.x;
  const int seg = bb >> 8;
  const int r = bb & 255;
  const int b = r >> 7;
  const int d_base = (r & 127) * 16;

  const float A_dn = -__expf(A_log[(d_base + c) * DSTATE + n]);

  float s = 0.f;
  {
    const int base = r * NSEG * 256 + t;
    for (int k = 0; k < seg; ++k)
      s = fmaf(pbuf[base + k * 256], s, ebuf[base + k * 256]);
  }

  __shared__ __align__(16) float dl[16 * 68];
  __shared__ __align__(16) float ul[16 * 68];
  __shared__ __align__(16) float Bl[16 * 68];
  __shared__ __align__(16) float Cl[16 * 68];
  __shared__ __align__(16) float yl[16 * 68];
  __shared__ __align__(16) float z_s[64 * 16];
  __shared__ float Dp_s[16];

  if (t < 16) Dp_s[t] = Dp[d_base + t];

  const int i_st = t >> 2;
  const int cc = (t & 3) * 4;

  for (int l0 = seg * SEGLEN; l0 < seg * SEGLEN + SEGLEN; l0 += 64) {
    const int row = b * SEQLEN + l0 + i_st;
    {
      float4 dv = *(const float4*)&delta[(size_t)row * DINNER + d_base + cc];
      float4 uv = *(const float4*)&u[(size_t)row * DINNER + d_base + cc];
      float4 Bv = *(const float4*)&x_dbl[(size_t)row * XPAD + DTRANK + cc];
      float4 Cv = *(const float4*)&x_dbl[(size_t)row * XPAD + DTRANK + DSTATE + cc];
      float4 zv = *(const float4*)&xz[(size_t)row * (2 * DINNER) + DINNER + d_base + cc];
      dl[(cc+0)*68 + i_st] = dv.x; dl[(cc+1)*68 + i_st] = dv.y;
      dl[(cc+2)*68 + i_st] = dv.z; dl[(cc+3)*68 + i_st] = dv.w;
      ul[(cc+0)*68 + i_st] = uv.x; ul[(cc+1)*68 + i_st] = uv.y;
      ul[(cc+2)*68 + i_st] = uv.z; ul[(cc+3)*68 + i_st] = uv.w;
      Bl[(cc+0)*68 + i_st] = Bv.x; Bl[(cc+1)*68 + i_st] = Bv.y;
      Bl[(cc+2)*68 + i_st] = Bv.z; Bl[(cc+3)*68 + i_st] = Bv.w;
      Cl[(cc+0)*68 + i_st] = Cv.x; Cl[(cc+1)*68 + i_st] = Cv.y;
      Cl[(cc+2)*68 + i_st] = Cv.z; Cl[(cc+3)*68 + i_st] = Cv.w;
      *(float4*)&z_s[t * 4] = zv;
    }
    __syncthreads();

#pragma unroll
    for (int i0 = 0; i0 < 64; i0 += 4) {
      f32x4 dv4 = *(const f32x4*)&dl[c * 68 + i0];
      f32x4 uv4 = *(const f32x4*)&ul[c * 68 + i0];
      f32x4 Bv4 = *(const f32x4*)&Bl[n * 68 + i0];
      f32x4 Cv4 = *(const f32x4*)&Cl[n * 68 + i0];
      f32x4 py;
#pragma unroll
      for (int rr = 0; rr < 4; ++rr) {
        float dA = __expf(dv4[rr] * A_dn);
        s = fmaf(dA, s, dv4[rr] * Bv4[rr] * uv4[rr]);
        py[rr] = row_sum16(s * Cv4[rr]);
      }
      if (n == 0) *(f32x4*)&yl[c * 68 + i0] = py;
    }
    __syncthreads();

#pragma unroll
    for (int k = 0; k < 4; ++k) {
      int o = t + 256 * k;
      int i = o >> 4, c2 = o & 15;
      float ssum = yl[c2 * 68 + i];
      float uv = ul[c2 * 68 + i];
      float zv = z_s[o];
      float yv = fmaf(uv, Dp_s[c2], ssum);
      yv *= zv / (1.f + __expf(-zv));
      y16[(size_t)(b * SEQLEN + l0 + i) * DINNER + d_base + c2] = (_Float16)yv;
    }
    __syncthreads();
  }
}

// ---------------------------------------------------------------------------
extern "C" void kernel_launch(void* const* d_in, const int* in_sizes, int n_in,
                              void* d_out, int out_size, void* d_ws, size_t ws_size,
                              hipStream_t stream)
{
  const float* hidden     = (const float*)d_in[0];
  const float* in_proj_w  = (const float*)d_in[1];
  const float* conv_w     = (const float*)d_in[2];
  const float* conv_b     = (const float*)d_in[3];
  const float* x_proj_w   = (const float*)d_in[4];
  const float* dt_proj_w  = (const float*)d_in[5];
  const float* dt_proj_b  = (const float*)d_in[6];
  const float* A_log      = (const float*)d_in[7];
  const float* Dp         = (const float*)d_in[8];
  const float* out_proj_w = (const float*)d_in[9];
  float* out = (float*)d_out;

  char* p = (char*)d_ws;
  float*    xz     = (float*)p;     p += (size_t)MROWS * 2 * DINNER * 4;  // 33.5MB
  float*    u32    = (float*)p;     p += (size_t)MROWS * DINNER * 4;
  float*    xdbl32 = (float*)p;     p += (size_t)MROWS * XPAD * 4;
  float*    delta  = (float*)p;     p += (size_t)MROWS * DINNER * 4;      // 16.8MB
  _Float16* h16    = (_Float16*)p;  p += (size_t)MROWS * DMODEL * 2;
  _Float16* win16  = (_Float16*)p;  p += (size_t)2 * DINNER * DMODEL * 2;
  _Float16* wout16 = (_Float16*)p;  p += (size_t)DMODEL * DINNER * 2;
  _Float16* wdt16  = (_Float16*)p;  p += (size_t)DINNER * DTRANK * 2;
  _Float16* wxp16  = (_Float16*)p;  p += (size_t)XPAD * DINNER * 2;
  _Float16* u16    = (_Float16*)p;  p += (size_t)MROWS * DINNER * 2;
  _Float16* xdbl16 = (_Float16*)p;  p += (size_t)MROWS * DTRANK * 2;
  _Float16* y16    = (_Float16*)p;  p += (size_t)MROWS * DINNER * 2;
  float*    pbuf   = (float*)p;     p += (size_t)256 * NSEG * 256 * 4;
  float*    ebuf   = (float*)p;     p += (size_t)256 * NSEG * 256 * 4;
  // lifetime-aliased partial buffers (no extra footprint):
  float*    xp_part  = delta;   // 16*2048*128*4 = 16.8MB; dead before dt-GEMM writes delta
  float*    out_part = xz;      // 4*2048*1024*4 = 33.5MB; xz dead after scan_part2

  // 0. all fp32->fp16 conversions in one launch
  f2h_all<<<(F2H_TOTAL + 255) / 256, 256, 0, stream>>>(
      hidden, in_proj_w, out_proj_w, dt_proj_w, x_proj_w,
      h16, win16, wout16, wdt16, wxp16);

  // 1. in_proj: xz = hidden @ in_proj_w^T  [2048, 4096], K=1024 — 1024 blocks
  hgemm64<0><<<dim3(2 * DINNER / 128, MROWS / 64, 1), 256, 0, stream>>>(
      h16, DMODEL, win16, DMODEL, xz, 2 * DINNER, DMODEL, nullptr, 0);

  // 2. conv + SiLU -> u32, u16
  conv_silu<<<(MROWS * DINNER) / 256, 256, 0, stream>>>(xz, conv_w, conv_b, u32, u16);

  // 3. x_proj: partials[z] = u @ x_proj_w^T chunk  [2048,128], split-K=16
  hgemm64<0><<<dim3(1, MROWS / 64, XP_SPLIT), 256, 0, stream>>>(
      u16, DINNER, wxp16, DINNER, xp_part, XPAD, DINNER, nullptr,
      (size_t)MROWS * XPAD);

  // 3b. reduce partials -> xdbl32 + f16 dt cols
  reduce_xdbl<<<(MROWS * XPAD / 4) / 256, 256, 0, stream>>>(xp_part, xdbl32, xdbl16);

  // 4. dt: delta = softplus(xdbl16 @ dt_proj_w^T + 2*b)  [2048,2048], K=64
  hgemm64<2><<<dim3(DINNER / 128, MROWS / 64, 1), 256, 0, stream>>>(
      xdbl16, DTRANK, wdt16, DTRANK, delta, DINNER, DTRANK, dt_proj_b, 0);

  // 5. selective scan, two-pass sequence-split -> y16
  scan_part1<<<256 * NSEG, 256, 0, stream>>>(delta, u32, xdbl32, A_log, pbuf, ebuf);
  scan_part2<<<256 * NSEG, 256, 0, stream>>>(delta, u32, xz, xdbl32, A_log, Dp,
                                             pbuf, ebuf, y16);

  // 6. out_proj: partials[z] = y @ out_proj_w^T chunk [2048,1024], split-K=4
  hgemm64<0><<<dim3(DMODEL / 128, MROWS / 64, OUT_SPLIT), 256, 0, stream>>>(
      y16, DINNER, wout16, DINNER, out_part, DMODEL, DINNER, nullptr,
      (size_t)MROWS * DMODEL);

  // 6b. reduce -> out
  reduce_out<<<(MROWS * DMODEL / 4) / 256, 256, 0, stream>>>(out_part, out);
}

// Round 6
// 293.889 us; speedup vs baseline: 2.6928x; 1.0106x over previous
//
#include <hip/hip_runtime.h>
#include <hip/hip_bf16.h>
#include <math.h>

#define BATCH   2
#define SEQLEN  1024
#define DMODEL  1024
#define DINNER  2048
#define DSTATE  16
#define DTRANK  64
#define XPAD    128             // padded x_dbl row stride (96 -> 128)
#define MROWS   (BATCH*SEQLEN)  // 2048
#define NSEG    8
#define SEGLEN  (SEQLEN/NSEG)   // 128
#define XP_SPLIT  16

typedef float    f32x4  __attribute__((ext_vector_type(4)));
typedef _Float16 f16x8  __attribute__((ext_vector_type(8)));
typedef _Float16 f16x4  __attribute__((ext_vector_type(4)));

// ---------------------------------------------------------------------------
// Pipelined fp16 MFMA GEMM, 64x128 tile, 256 thr (4 waves, each 64m x 32n).
// K-loop: one barrier/iter; global loads for tile k+1 go to REGISTERS right
// after the barrier (latency flies over the MFMA phase; compiler emits exact
// vmcnt(N) at the ds_write, not vmcnt(0) at a barrier), then ds_write into
// the other LDS buffer. LDS [buf2][kb4][row][8]: frag ds_read_b128 <=2-way.
// EPI 0: fp32 store (+zstride partials)  2: softplus(acc+2*bias) fp32
// EPI 4: f16 store (in_proj -> xz16)
// ---------------------------------------------------------------------------
template<int EPI>
__global__ __launch_bounds__(256) void pgemm(
    const _Float16* __restrict__ A, int lda,
    const _Float16* __restrict__ W, int ldw,
    float* __restrict__ C, int ldc, int K,
    const float* __restrict__ bias, _Float16* __restrict__ C16, size_t zstride)
{
  __shared__ _Float16 As[2][2048];   // [buf][kb4][row64][8]
  __shared__ _Float16 Bs[2][4096];   // [buf][kb4][row128][8]

  const int t  = threadIdx.x;
  const int m0 = blockIdx.y * 64, n0 = blockIdx.x * 128;
  const int kchunk = K / gridDim.z;
  const int kbeg = blockIdx.z * kchunk;
  const int nIter = kchunk / 32;

  const _Float16* gA = A + (size_t)(m0 + (t & 63)) * lda + kbeg + (t >> 6) * 8;
  const _Float16* gB = W + (size_t)(n0 + (t & 127)) * ldw + kbeg + (t >> 7) * 8;

  // prologue: tile 0 regs -> LDS buf 0
  {
    f16x8 ra  = *(const f16x8*)gA;
    f16x8 rb0 = *(const f16x8*)gB;
    f16x8 rb1 = *(const f16x8*)(gB + 16);
    gA += 32; gB += 32;
    *(f16x8*)&As[0][t * 8]        = ra;
    *(f16x8*)&Bs[0][t * 8]        = rb0;
    *(f16x8*)&Bs[0][2048 + t * 8] = rb1;
  }

  const int lane = t & 63, wvi = t >> 6;
  const int wn = wvi * 32;
  const int lm = lane & 15, lk = lane >> 4;

  f32x4 acc[4][2] = {};

  for (int it = 0; it < nIter; ++it) {
    __syncthreads();
    const bool more = (it + 1 < nIter);
    f16x8 na, nb0, nb1;
    if (more) {                       // prefetch next tile into regs NOW
      na  = *(const f16x8*)gA;
      nb0 = *(const f16x8*)gB;
      nb1 = *(const f16x8*)(gB + 16);
      gA += 32; gB += 32;
    }
    const int cb = it & 1;
    f16x8 av[4], bv[2];
#pragma unroll
    for (int i = 0; i < 4; ++i)
      av[i] = *(const f16x8*)&As[cb][lk * 512 + (i * 16 + lm) * 8];
#pragma unroll
    for (int j = 0; j < 2; ++j)
      bv[j] = *(const f16x8*)&Bs[cb][lk * 1024 + (wn + j * 16 + lm) * 8];
#pragma unroll
    for (int i = 0; i < 4; ++i)
#pragma unroll
      for (int j = 0; j < 2; ++j)
        acc[i][j] = __builtin_amdgcn_mfma_f32_16x16x32_f16(av[i], bv[j], acc[i][j], 0, 0, 0);
    if (more) {                       // exact-vmcnt wait lands HERE, post-MFMA
      const int nb = (it + 1) & 1;
      *(f16x8*)&As[nb][t * 8]        = na;
      *(f16x8*)&Bs[nb][t * 8]        = nb0;
      *(f16x8*)&Bs[nb][2048 + t * 8] = nb1;
    }
  }

  // C/D layout: col = lane&15, row = (lane>>4)*4 + reg
  float* Cz = C + (size_t)blockIdx.z * zstride;
#pragma unroll
  for (int i = 0; i < 4; ++i) {
    const int mrow = m0 + i * 16 + lk * 4;
#pragma unroll
    for (int j = 0; j < 2; ++j) {
      const int col = n0 + wn + j * 16 + lm;
#pragma unroll
      for (int r = 0; r < 4; ++r) {
        float v = acc[i][j][r];
        size_t off = (size_t)(mrow + r) * ldc + col;
        if constexpr (EPI == 0) {
          Cz[off] = v;
        } else if constexpr (EPI == 2) {
          float x = v + 2.f * bias[col];
          Cz[off] = (x > 20.f) ? x : log1pf(__expf(x));
        } else {  // EPI == 4: f16 store
          C16[off] = (_Float16)v;
        }
      }
    }
  }
}

// ---------------------------------------------------------------------------
// Fused fp32 -> fp16 conversion of all weights + hidden (one launch).
// ---------------------------------------------------------------------------
#define R0 (MROWS * DMODEL / 4)            // hidden:      524288
#define R1 (2 * DINNER * DMODEL / 4)       // in_proj_w:  1048576
#define R2 (DMODEL * DINNER / 4)           // out_proj_w:  524288
#define R3 (DINNER * DTRANK / 4)           // dt_proj_w:    32768
#define R4 (XPAD * DINNER / 4)             // x_proj_w pad: 65536
#define F2H_TOTAL (R0 + R1 + R2 + R3 + R4)

__global__ __launch_bounds__(256) void f2h_all(
    const float* __restrict__ hid, const float* __restrict__ w_in,
    const float* __restrict__ w_out, const float* __restrict__ w_dt,
    const float* __restrict__ w_xp,
    _Float16* __restrict__ hid16, _Float16* __restrict__ w_in16,
    _Float16* __restrict__ w_out16, _Float16* __restrict__ w_dt16,
    _Float16* __restrict__ w_xp16)
{
  int i = blockIdx.x * 256 + threadIdx.x;
  const float* src; _Float16* dst; int off;
  if (i < R0)                     { src = hid;   dst = hid16;   off = i; }
  else if (i < R0+R1)             { src = w_in;  dst = w_in16;  off = i - R0; }
  else if (i < R0+R1+R2)          { src = w_out; dst = w_out16; off = i - (R0+R1); }
  else if (i < R0+R1+R2+R3)       { src = w_dt;  dst = w_dt16;  off = i - (R0+R1+R2); }
  else if (i < F2H_TOTAL) {
    off = i - (R0+R1+R2+R3);
    int r = (off * 4) >> 11;                 // row of padded [128, 2048]
    f16x4 h = {0, 0, 0, 0};
    if (r < 96) {
      float4 v = ((const float4*)w_xp)[off];
      h = (f16x4){(_Float16)v.x, (_Float16)v.y, (_Float16)v.z, (_Float16)v.w};
    }
    ((f16x4*)w_xp16)[off] = h;
    return;
  } else return;
  float4 v = ((const float4*)src)[off];
  ((f16x4*)dst)[off] = (f16x4){(_Float16)v.x, (_Float16)v.y, (_Float16)v.z, (_Float16)v.w};
}

// ---------------------------------------------------------------------------
// Reduce x_proj split-K partials -> xdbl32 [2048,128] + f16 dt-cols [2048,64]
// ---------------------------------------------------------------------------
__global__ __launch_bounds__(256) void reduce_xdbl(
    const float* __restrict__ part,       // [16][2048*128]
    float* __restrict__ xdbl32, _Float16* __restrict__ xdbl16)
{
  int i = blockIdx.x * 256 + threadIdx.x;          // float4 units, < 65536
  f32x4 s = ((const f32x4*)part)[i];
#pragma unroll
  for (int z = 1; z < XP_SPLIT; ++z)
    s += ((const f32x4*)part)[(size_t)z * (MROWS * XPAD / 4) + i];
  ((f32x4*)xdbl32)[i] = s;
  int col4 = (i & 31) * 4;
  if (col4 < DTRANK) {
    int row = i >> 5;
    *(f16x4*)&xdbl16[(size_t)row * DTRANK + col4] =
        (f16x4){(_Float16)s.x, (_Float16)s.y, (_Float16)s.z, (_Float16)s.w};
  }
}

// ---------------------------------------------------------------------------
// Causal depthwise conv (k=4) + bias + SiLU; xz is f16 now; writes u16.
// ---------------------------------------------------------------------------
__global__ __launch_bounds__(256) void conv_silu(
    const _Float16* __restrict__ xz16,
    const float* __restrict__ conv_w,
    const float* __restrict__ conv_b,
    _Float16* __restrict__ u16)
{
  const int idx = blockIdx.x * 256 + threadIdx.x;  // row*DINNER + d
  const int d   = idx & (DINNER - 1);
  const int row = idx >> 11;
  const int l   = row & (SEQLEN - 1);
  float s = conv_b[d];
#pragma unroll
  for (int k = 0; k < 4; ++k) {
    int lt = l + k - 3;
    if (lt >= 0)
      s = fmaf((float)xz16[(size_t)(row + k - 3) * (2 * DINNER) + d],
               conv_w[d * 4 + k], s);
  }
  float v = s / (1.f + __expf(-s));
  u16[idx] = (_Float16)v;
}

// ---------------------------------------------------------------------------
// Selective scan, two-pass sequence-split (u and z now f16).
// ---------------------------------------------------------------------------
__device__ __forceinline__ float row_sum16(float x) {
  int v = __builtin_bit_cast(int, x);
  x += __builtin_bit_cast(float, __builtin_amdgcn_update_dpp(0, v, 0x128, 0xF, 0xF, true)); // row_ror:8
  v = __builtin_bit_cast(int, x);
  x += __builtin_bit_cast(float, __builtin_amdgcn_update_dpp(0, v, 0x124, 0xF, 0xF, true)); // row_ror:4
  v = __builtin_bit_cast(int, x);
  x += __builtin_bit_cast(float, __builtin_amdgcn_update_dpp(0, v, 0x4E, 0xF, 0xF, true));  // quad xor2
  v = __builtin_bit_cast(int, x);
  x += __builtin_bit_cast(float, __builtin_amdgcn_update_dpp(0, v, 0xB1, 0xF, 0xF, true));  // quad xor1
  return x;
}

__global__ __launch_bounds__(256) void scan_part1(
    const float* __restrict__ delta,
    const _Float16* __restrict__ u16,
    const float* __restrict__ x_dbl,
    const float* __restrict__ A_log,
    float* __restrict__ pbuf, float* __restrict__ ebuf)
{
  const int t = threadIdx.x;
  const int c = t >> 4, n = t & 15;
  const int bb = blockIdx.x;
  const int seg = bb >> 8;
  const int r = bb & 255;
  const int b = r >> 7;
  const int d_base = (r & 127) * 16;

  const float A_dn = -__expf(A_log[(d_base + c) * DSTATE + n]);
  float s = 0.f, p = 1.f;

  __shared__ __align__(16) float dl[16 * 68];
  __shared__ __align__(16) float ul[16 * 68];
  __shared__ __align__(16) float Bl[16 * 68];

  const int i_st = t >> 2;
  const int cc = (t & 3) * 4;

  for (int l0 = seg * SEGLEN; l0 < seg * SEGLEN + SEGLEN; l0 += 64) {
    const int row = b * SEQLEN + l0 + i_st;
    {
      float4 dv = *(const float4*)&delta[(size_t)row * DINNER + d_base + cc];
      f16x4  uh = *(const f16x4*)&u16[(size_t)row * DINNER + d_base + cc];
      float4 Bv = *(const float4*)&x_dbl[(size_t)row * XPAD + DTRANK + cc];
      dl[(cc+0)*68 + i_st] = dv.x; dl[(cc+1)*68 + i_st] = dv.y;
      dl[(cc+2)*68 + i_st] = dv.z; dl[(cc+3)*68 + i_st] = dv.w;
      ul[(cc+0)*68 + i_st] = (float)uh[0]; ul[(cc+1)*68 + i_st] = (float)uh[1];
      ul[(cc+2)*68 + i_st] = (float)uh[2]; ul[(cc+3)*68 + i_st] = (float)uh[3];
      Bl[(cc+0)*68 + i_st] = Bv.x; Bl[(cc+1)*68 + i_st] = Bv.y;
      Bl[(cc+2)*68 + i_st] = Bv.z; Bl[(cc+3)*68 + i_st] = Bv.w;
    }
    __syncthreads();
#pragma unroll
    for (int i0 = 0; i0 < 64; i0 += 4) {
      f32x4 dv4 = *(const f32x4*)&dl[c * 68 + i0];
      f32x4 uv4 = *(const f32x4*)&ul[c * 68 + i0];
      f32x4 Bv4 = *(const f32x4*)&Bl[n * 68 + i0];
#pragma unroll
      for (int rr = 0; rr < 4; ++rr) {
        float dA = __expf(dv4[rr] * A_dn);
        s = fmaf(dA, s, dv4[rr] * Bv4[rr] * uv4[rr]);
        p *= dA;
      }
    }
    __syncthreads();
  }
  const int peIdx = (r * NSEG + seg) * 256 + t;
  pbuf[peIdx] = p;
  ebuf[peIdx] = s;
}

__global__ __launch_bounds__(256) void scan_part2(
    const float* __restrict__ delta,
    const _Float16* __restrict__ u16,
    const _Float16* __restrict__ xz16,   // z = xz16[:, DINNER:]
    const float* __restrict__ x_dbl,
    const float* __restrict__ A_log,
    const float* __restrict__ Dp,
    const float* __restrict__ pbuf,
    const float* __restrict__ ebuf,
    _Float16* __restrict__ y16)
{
  const int t = threadIdx.x;
  const int c = t >> 4, n = t & 15;
  const int bb = blockIdx.x;
  const int seg = bb >> 8;
  const int r = bb & 255;
  const int b = r >> 7;
  const int d_base = (r & 127) * 16;

  const float A_dn = -__expf(A_log[(d_base + c) * DSTATE + n]);

  float s = 0.f;
  {
    const int base = r * NSEG * 256 + t;
    for (int k = 0; k < seg; ++k)
      s = fmaf(pbuf[base + k * 256], s, ebuf[base + k * 256]);
  }

  __shared__ __align__(16) float dl[16 * 68];
  __shared__ __align__(16) float ul[16 * 68];
  __shared__ __align__(16) float Bl[16 * 68];
  __shared__ __align__(16) float Cl[16 * 68];
  __shared__ __align__(16) float yl[16 * 68];
  __shared__ __align__(16) float z_s[64 * 16];
  __shared__ float Dp_s[16];

  if (t < 16) Dp_s[t] = Dp[d_base + t];

  const int i_st = t >> 2;
  const int cc = (t & 3) * 4;

  for (int l0 = seg * SEGLEN; l0 < seg * SEGLEN + SEGLEN; l0 += 64) {
    const int row = b * SEQLEN + l0 + i_st;
    {
      float4 dv = *(const float4*)&delta[(size_t)row * DINNER + d_base + cc];
      f16x4  uh = *(const f16x4*)&u16[(size_t)row * DINNER + d_base + cc];
      float4 Bv = *(const float4*)&x_dbl[(size_t)row * XPAD + DTRANK + cc];
      float4 Cv = *(const float4*)&x_dbl[(size_t)row * XPAD + DTRANK + DSTATE + cc];
      f16x4  zh = *(const f16x4*)&xz16[(size_t)row * (2 * DINNER) + DINNER + d_base + cc];
      dl[(cc+0)*68 + i_st] = dv.x; dl[(cc+1)*68 + i_st] = dv.y;
      dl[(cc+2)*68 + i_st] = dv.z; dl[(cc+3)*68 + i_st] = dv.w;
      ul[(cc+0)*68 + i_st] = (float)uh[0]; ul[(cc+1)*68 + i_st] = (float)uh[1];
      ul[(cc+2)*68 + i_st] = (float)uh[2]; ul[(cc+3)*68 + i_st] = (float)uh[3];
      Bl[(cc+0)*68 + i_st] = Bv.x; Bl[(cc+1)*68 + i_st] = Bv.y;
      Bl[(cc+2)*68 + i_st] = Bv.z; Bl[(cc+3)*68 + i_st] = Bv.w;
      Cl[(cc+0)*68 + i_st] = Cv.x; Cl[(cc+1)*68 + i_st] = Cv.y;
      Cl[(cc+2)*68 + i_st] = Cv.z; Cl[(cc+3)*68 + i_st] = Cv.w;
      float4 zv = make_float4((float)zh[0], (float)zh[1], (float)zh[2], (float)zh[3]);
      *(float4*)&z_s[t * 4] = zv;
    }
    __syncthreads();

#pragma unroll
    for (int i0 = 0; i0 < 64; i0 += 4) {
      f32x4 dv4 = *(const f32x4*)&dl[c * 68 + i0];
      f32x4 uv4 = *(const f32x4*)&ul[c * 68 + i0];
      f32x4 Bv4 = *(const f32x4*)&Bl[n * 68 + i0];
      f32x4 Cv4 = *(const f32x4*)&Cl[n * 68 + i0];
      f32x4 py;
#pragma unroll
      for (int rr = 0; rr < 4; ++rr) {
        float dA = __expf(dv4[rr] * A_dn);
        s = fmaf(dA, s, dv4[rr] * Bv4[rr] * uv4[rr]);
        py[rr] = row_sum16(s * Cv4[rr]);
      }
      if (n == 0) *(f32x4*)&yl[c * 68 + i0] = py;
    }
    __syncthreads();

#pragma unroll
    for (int k = 0; k < 4; ++k) {
      int o = t + 256 * k;
      int i = o >> 4, c2 = o & 15;
      float ssum = yl[c2 * 68 + i];
      float uv = ul[c2 * 68 + i];
      float zv = z_s[o];
      float yv = fmaf(uv, Dp_s[c2], ssum);
      yv *= zv / (1.f + __expf(-zv));
      y16[(size_t)(b * SEQLEN + l0 + i) * DINNER + d_base + c2] = (_Float16)yv;
    }
    __syncthreads();
  }
}

// ---------------------------------------------------------------------------
extern "C" void kernel_launch(void* const* d_in, const int* in_sizes, int n_in,
                              void* d_out, int out_size, void* d_ws, size_t ws_size,
                              hipStream_t stream)
{
  const float* hidden     = (const float*)d_in[0];
  const float* in_proj_w  = (const float*)d_in[1];
  const float* conv_w     = (const float*)d_in[2];
  const float* conv_b     = (const float*)d_in[3];
  const float* x_proj_w   = (const float*)d_in[4];
  const float* dt_proj_w  = (const float*)d_in[5];
  const float* dt_proj_b  = (const float*)d_in[6];
  const float* A_log      = (const float*)d_in[7];
  const float* Dp         = (const float*)d_in[8];
  const float* out_proj_w = (const float*)d_in[9];
  float* out = (float*)d_out;

  char* p = (char*)d_ws;
  _Float16* xz16   = (_Float16*)p;  p += (size_t)MROWS * 2 * DINNER * 2;  // 16.8MB
  _Float16* u16    = (_Float16*)p;  p += (size_t)MROWS * DINNER * 2;      // 8.4MB
  float*    xdbl32 = (float*)p;     p += (size_t)MROWS * XPAD * 4;        // 1.05MB
  float*    delta  = (float*)p;     p += (size_t)MROWS * DINNER * 4;      // 16.8MB
  _Float16* h16    = (_Float16*)p;  p += (size_t)MROWS * DMODEL * 2;
  _Float16* win16  = (_Float16*)p;  p += (size_t)2 * DINNER * DMODEL * 2;
  _Float16* wout16 = (_Float16*)p;  p += (size_t)DMODEL * DINNER * 2;
  _Float16* wdt16  = (_Float16*)p;  p += (size_t)DINNER * DTRANK * 2;
  _Float16* wxp16  = (_Float16*)p;  p += (size_t)XPAD * DINNER * 2;
  _Float16* xdbl16 = (_Float16*)p;  p += (size_t)MROWS * DTRANK * 2;
  _Float16* y16    = (_Float16*)p;  p += (size_t)MROWS * DINNER * 2;
  float*    pbuf   = (float*)p;     p += (size_t)256 * NSEG * 256 * 4;
  float*    ebuf   = (float*)p;     p += (size_t)256 * NSEG * 256 * 4;
  // x_proj split-K partials alias delta (dead until dt-GEMM writes it):
  float*    xp_part = delta;        // 16 * 2048*128 * 4 = 16.8MB exactly

  // 0. all fp32->fp16 conversions in one launch
  f2h_all<<<(F2H_TOTAL + 255) / 256, 256, 0, stream>>>(
      hidden, in_proj_w, out_proj_w, dt_proj_w, x_proj_w,
      h16, win16, wout16, wdt16, wxp16);

  // 1. in_proj: xz16 = f16(hidden @ in_proj_w^T)  [2048, 4096], K=1024
  pgemm<4><<<dim3(2 * DINNER / 128, MROWS / 64, 1), 256, 0, stream>>>(
      h16, DMODEL, win16, DMODEL, nullptr, 2 * DINNER, DMODEL, nullptr, xz16, 0);

  // 2. conv + SiLU -> u16
  conv_silu<<<(MROWS * DINNER) / 256, 256, 0, stream>>>(xz16, conv_w, conv_b, u16);

  // 3. x_proj: partials[z] = u @ x_proj_w^T chunk  [2048,128], split-K=16
  pgemm<0><<<dim3(1, MROWS / 64, XP_SPLIT), 256, 0, stream>>>(
      u16, DINNER, wxp16, DINNER, xp_part, XPAD, DINNER, nullptr, nullptr,
      (size_t)MROWS * XPAD);

  // 3b. reduce partials -> xdbl32 + f16 dt cols
  reduce_xdbl<<<(MROWS * XPAD / 4) / 256, 256, 0, stream>>>(xp_part, xdbl32, xdbl16);

  // 4. dt: delta = softplus(xdbl16 @ dt_proj_w^T + 2*b)  [2048,2048], K=64
  pgemm<2><<<dim3(DINNER / 128, MROWS / 64, 1), 256, 0, stream>>>(
      xdbl16, DTRANK, wdt16, DTRANK, delta, DINNER, DTRANK, dt_proj_b, nullptr, 0);

  // 5. selective scan, two-pass sequence-split -> y16
  scan_part1<<<256 * NSEG, 256, 0, stream>>>(delta, u16, xdbl32, A_log, pbuf, ebuf);
  scan_part2<<<256 * NSEG, 256, 0, stream>>>(delta, u16, xz16, xdbl32, A_log, Dp,
                                             pbuf, ebuf, y16);

  // 6. out_proj: out = y @ out_proj_w^T [2048, 1024], K=2048, no split-K
  pgemm<0><<<dim3(DMODEL / 128, MROWS / 64, 1), 256, 0, stream>>>(
      y16, DINNER, wout16, DINNER, out, DMODEL, DINNER, nullptr, nullptr, 0);
}

// Round 7
// 252.622 us; speedup vs baseline: 3.1327x; 1.1634x over previous
//
#include <hip/hip_runtime.h>
#include <hip/hip_bf16.h>
#include <math.h>

#define BATCH   2
#define SEQLEN  1024
#define DMODEL  1024
#define DINNER  2048
#define DSTATE  16
#define DTRANK  64
#define XPAD    128             // padded x_dbl row stride (96 -> 128)
#define MROWS   (BATCH*SEQLEN)  // 2048
#define NSEG    8
#define SEGLEN  (SEQLEN/NSEG)   // 128
#define XP_SPLIT  16

typedef float    f32x4  __attribute__((ext_vector_type(4)));
typedef _Float16 f16x8  __attribute__((ext_vector_type(8)));
typedef _Float16 f16x4  __attribute__((ext_vector_type(4)));

// ---------------------------------------------------------------------------
// Pipelined fp16 MFMA GEMM, 64x128 tile, BK=64, 256 thr (4 waves, 64m x 32n).
// Staging is LINE-COALESCED: thread t -> (row = t>>3, k16 = t&7); 8 consecutive
// lanes read one full 128B row-line (vs round-6's 64-lines-per-wave scatter).
// K-loop: 1 barrier/iter; next tile -> regs right after barrier (exact-vmcnt
// wait lands at the ds_write after MFMA), double-buffered LDS.
// LDS [buf][kb8][row][8] halves, plane padded +8 halves: staging writes and
// frag ds_read_b128 both <=2-way bank-aliased.
// EPI 0: fp32 store (+zstride partials)  2: softplus(acc+2*bias)  4: f16 store
// ---------------------------------------------------------------------------
template<int EPI>
__global__ __launch_bounds__(256) void pgemm(
    const _Float16* __restrict__ A, int lda,
    const _Float16* __restrict__ W, int ldw,
    float* __restrict__ C, int ldc, int K,
    const float* __restrict__ bias, _Float16* __restrict__ C16, size_t zstride)
{
  constexpr int APS = 520;    // A kb-plane stride (halves): 64*8 + 8 pad
  constexpr int BPS = 1032;   // B kb-plane stride: 128*8 + 8 pad
  __shared__ _Float16 As[2][8 * APS];   // 16.6 KB
  __shared__ _Float16 Bs[2][8 * BPS];   // 33.0 KB

  const int t  = threadIdx.x;
  const int m0 = blockIdx.y * 64, n0 = blockIdx.x * 128;
  const int kchunk = K / gridDim.z;
  const int kbeg = blockIdx.z * kchunk;
  const int nIter = kchunk / 64;

  const int kb = t & 7;       // 16B chunk within the 128B row-line
  const int r0 = t >> 3;      // base row 0..31
  const _Float16* gA = A + (size_t)(m0 + r0) * lda + kbeg + kb * 8;
  const _Float16* gB = W + (size_t)(n0 + r0) * ldw + kbeg + kb * 8;
  const size_t a32 = (size_t)32 * lda;
  const size_t b32 = (size_t)32 * ldw;
  const int aoff = kb * APS + r0 * 8;
  const int boff = kb * BPS + r0 * 8;

  // prologue: tile 0 -> regs -> LDS buf 0
  {
    f16x8 a0 = *(const f16x8*)(gA);
    f16x8 a1 = *(const f16x8*)(gA + a32);
    f16x8 b0 = *(const f16x8*)(gB);
    f16x8 b1 = *(const f16x8*)(gB + b32);
    f16x8 b2 = *(const f16x8*)(gB + 2 * b32);
    f16x8 b3 = *(const f16x8*)(gB + 3 * b32);
    gA += 64; gB += 64;
    *(f16x8*)&As[0][aoff]       = a0;
    *(f16x8*)&As[0][aoff + 256] = a1;   // row+32
    *(f16x8*)&Bs[0][boff]       = b0;
    *(f16x8*)&Bs[0][boff + 256] = b1;
    *(f16x8*)&Bs[0][boff + 512] = b2;
    *(f16x8*)&Bs[0][boff + 768] = b3;
  }

  const int lane = t & 63, wvi = t >> 6;
  const int wn = wvi * 32;
  const int lm = lane & 15, lk = lane >> 4;

  f32x4 acc[4][2] = {};

  for (int it = 0; it < nIter; ++it) {
    __syncthreads();
    const bool more = (it + 1 < nIter);
    f16x8 a0, a1, b0, b1, b2, b3;
    if (more) {                 // prefetch next tile into regs NOW
      a0 = *(const f16x8*)(gA);
      a1 = *(const f16x8*)(gA + a32);
      b0 = *(const f16x8*)(gB);
      b1 = *(const f16x8*)(gB + b32);
      b2 = *(const f16x8*)(gB + 2 * b32);
      b3 = *(const f16x8*)(gB + 3 * b32);
      gA += 64; gB += 64;
    }
    const int cb = it & 1;
#pragma unroll
    for (int s = 0; s < 2; ++s) {       // two 16x16x32 k-steps per BK=64 tile
      f16x8 av[4], bv[2];
#pragma unroll
      for (int i = 0; i < 4; ++i)
        av[i] = *(const f16x8*)&As[cb][(s * 4 + lk) * APS + (i * 16 + lm) * 8];
#pragma unroll
      for (int j = 0; j < 2; ++j)
        bv[j] = *(const f16x8*)&Bs[cb][(s * 4 + lk) * BPS + (wn + j * 16 + lm) * 8];
#pragma unroll
      for (int i = 0; i < 4; ++i)
#pragma unroll
        for (int j = 0; j < 2; ++j)
          acc[i][j] = __builtin_amdgcn_mfma_f32_16x16x32_f16(av[i], bv[j], acc[i][j], 0, 0, 0);
    }
    if (more) {                 // exact-vmcnt wait lands HERE, post-MFMA
      const int nb = (it + 1) & 1;
      *(f16x8*)&As[nb][aoff]       = a0;
      *(f16x8*)&As[nb][aoff + 256] = a1;
      *(f16x8*)&Bs[nb][boff]       = b0;
      *(f16x8*)&Bs[nb][boff + 256] = b1;
      *(f16x8*)&Bs[nb][boff + 512] = b2;
      *(f16x8*)&Bs[nb][boff + 768] = b3;
    }
  }

  // C/D layout: col = lane&15, row = (lane>>4)*4 + reg
  float* Cz = C + (size_t)blockIdx.z * zstride;
#pragma unroll
  for (int i = 0; i < 4; ++i) {
    const int mrow = m0 + i * 16 + lk * 4;
#pragma unroll
    for (int j = 0; j < 2; ++j) {
      const int col = n0 + wn + j * 16 + lm;
#pragma unroll
      for (int r = 0; r < 4; ++r) {
        float v = acc[i][j][r];
        size_t off = (size_t)(mrow + r) * ldc + col;
        if constexpr (EPI == 0) {
          Cz[off] = v;
        } else if constexpr (EPI == 2) {
          float x = v + 2.f * bias[col];
          Cz[off] = (x > 20.f) ? x : log1pf(__expf(x));
        } else {  // EPI == 4: f16 store
          C16[off] = (_Float16)v;
        }
      }
    }
  }
}

// ---------------------------------------------------------------------------
// Fused fp32 -> fp16 conversion of all weights + hidden (one launch).
// ---------------------------------------------------------------------------
#define R0 (MROWS * DMODEL / 4)            // hidden:      524288
#define R1 (2 * DINNER * DMODEL / 4)       // in_proj_w:  1048576
#define R2 (DMODEL * DINNER / 4)           // out_proj_w:  524288
#define R3 (DINNER * DTRANK / 4)           // dt_proj_w:    32768
#define R4 (XPAD * DINNER / 4)             // x_proj_w pad: 65536
#define F2H_TOTAL (R0 + R1 + R2 + R3 + R4)

__global__ __launch_bounds__(256) void f2h_all(
    const float* __restrict__ hid, const float* __restrict__ w_in,
    const float* __restrict__ w_out, const float* __restrict__ w_dt,
    const float* __restrict__ w_xp,
    _Float16* __restrict__ hid16, _Float16* __restrict__ w_in16,
    _Float16* __restrict__ w_out16, _Float16* __restrict__ w_dt16,
    _Float16* __restrict__ w_xp16)
{
  int i = blockIdx.x * 256 + threadIdx.x;
  const float* src; _Float16* dst; int off;
  if (i < R0)                     { src = hid;   dst = hid16;   off = i; }
  else if (i < R0+R1)             { src = w_in;  dst = w_in16;  off = i - R0; }
  else if (i < R0+R1+R2)          { src = w_out; dst = w_out16; off = i - (R0+R1); }
  else if (i < R0+R1+R2+R3)       { src = w_dt;  dst = w_dt16;  off = i - (R0+R1+R2); }
  else if (i < F2H_TOTAL) {
    off = i - (R0+R1+R2+R3);
    int r = (off * 4) >> 11;                 // row of padded [128, 2048]
    f16x4 h = {0, 0, 0, 0};
    if (r < 96) {
      float4 v = ((const float4*)w_xp)[off];
      h = (f16x4){(_Float16)v.x, (_Float16)v.y, (_Float16)v.z, (_Float16)v.w};
    }
    ((f16x4*)w_xp16)[off] = h;
    return;
  } else return;
  float4 v = ((const float4*)src)[off];
  ((f16x4*)dst)[off] = (f16x4){(_Float16)v.x, (_Float16)v.y, (_Float16)v.z, (_Float16)v.w};
}

// ---------------------------------------------------------------------------
// Reduce x_proj split-K partials -> xdbl32 [2048,128] + f16 dt-cols [2048,64]
// ---------------------------------------------------------------------------
__global__ __launch_bounds__(256) void reduce_xdbl(
    const float* __restrict__ part,       // [16][2048*128]
    float* __restrict__ xdbl32, _Float16* __restrict__ xdbl16)
{
  int i = blockIdx.x * 256 + threadIdx.x;          // float4 units, < 65536
  f32x4 s = ((const f32x4*)part)[i];
#pragma unroll
  for (int z = 1; z < XP_SPLIT; ++z)
    s += ((const f32x4*)part)[(size_t)z * (MROWS * XPAD / 4) + i];
  ((f32x4*)xdbl32)[i] = s;
  int col4 = (i & 31) * 4;
  if (col4 < DTRANK) {
    int row = i >> 5;
    *(f16x4*)&xdbl16[(size_t)row * DTRANK + col4] =
        (f16x4){(_Float16)s.x, (_Float16)s.y, (_Float16)s.z, (_Float16)s.w};
  }
}

// ---------------------------------------------------------------------------
// Causal depthwise conv (k=4) + bias + SiLU; xz is f16; writes u16.
// ---------------------------------------------------------------------------
__global__ __launch_bounds__(256) void conv_silu(
    const _Float16* __restrict__ xz16,
    const float* __restrict__ conv_w,
    const float* __restrict__ conv_b,
    _Float16* __restrict__ u16)
{
  const int idx = blockIdx.x * 256 + threadIdx.x;  // row*DINNER + d
  const int d   = idx & (DINNER - 1);
  const int row = idx >> 11;
  const int l   = row & (SEQLEN - 1);
  float s = conv_b[d];
#pragma unroll
  for (int k = 0; k < 4; ++k) {
    int lt = l + k - 3;
    if (lt >= 0)
      s = fmaf((float)xz16[(size_t)(row + k - 3) * (2 * DINNER) + d],
               conv_w[d * 4 + k], s);
  }
  float v = s / (1.f + __expf(-s));
  u16[idx] = (_Float16)v;
}

// ---------------------------------------------------------------------------
// Selective scan, two-pass sequence-split.
// ---------------------------------------------------------------------------
__device__ __forceinline__ float row_sum16(float x) {
  int v = __builtin_bit_cast(int, x);
  x += __builtin_bit_cast(float, __builtin_amdgcn_update_dpp(0, v, 0x128, 0xF, 0xF, true)); // row_ror:8
  v = __builtin_bit_cast(int, x);
  x += __builtin_bit_cast(float, __builtin_amdgcn_update_dpp(0, v, 0x124, 0xF, 0xF, true)); // row_ror:4
  v = __builtin_bit_cast(int, x);
  x += __builtin_bit_cast(float, __builtin_amdgcn_update_dpp(0, v, 0x4E, 0xF, 0xF, true));  // quad xor2
  v = __builtin_bit_cast(int, x);
  x += __builtin_bit_cast(float, __builtin_amdgcn_update_dpp(0, v, 0xB1, 0xF, 0xF, true));  // quad xor1
  return x;
}

__global__ __launch_bounds__(256) void scan_part1(
    const float* __restrict__ delta,
    const _Float16* __restrict__ u16,
    const float* __restrict__ x_dbl,
    const float* __restrict__ A_log,
    float* __restrict__ pbuf, float* __restrict__ ebuf)
{
  const int t = threadIdx.x;
  const int c = t >> 4, n = t & 15;
  const int bb = blockIdx.x;
  const int seg = bb >> 8;
  const int r = bb & 255;
  const int b = r >> 7;
  const int d_base = (r & 127) * 16;

  const float A_dn = -__expf(A_log[(d_base + c) * DSTATE + n]);
  float s = 0.f, p = 1.f;

  __shared__ __align__(16) float dl[16 * 68];
  __shared__ __align__(16) float ul[16 * 68];
  __shared__ __align__(16) float Bl[16 * 68];

  const int i_st = t >> 2;
  const int cc = (t & 3) * 4;

  for (int l0 = seg * SEGLEN; l0 < seg * SEGLEN + SEGLEN; l0 += 64) {
    const int row = b * SEQLEN + l0 + i_st;
    {
      float4 dv = *(const float4*)&delta[(size_t)row * DINNER + d_base + cc];
      f16x4  uh = *(const f16x4*)&u16[(size_t)row * DINNER + d_base + cc];
      float4 Bv = *(const float4*)&x_dbl[(size_t)row * XPAD + DTRANK + cc];
      dl[(cc+0)*68 + i_st] = dv.x; dl[(cc+1)*68 + i_st] = dv.y;
      dl[(cc+2)*68 + i_st] = dv.z; dl[(cc+3)*68 + i_st] = dv.w;
      ul[(cc+0)*68 + i_st] = (float)uh[0]; ul[(cc+1)*68 + i_st] = (float)uh[1];
      ul[(cc+2)*68 + i_st] = (float)uh[2]; ul[(cc+3)*68 + i_st] = (float)uh[3];
      Bl[(cc+0)*68 + i_st] = Bv.x; Bl[(cc+1)*68 + i_st] = Bv.y;
      Bl[(cc+2)*68 + i_st] = Bv.z; Bl[(cc+3)*68 + i_st] = Bv.w;
    }
    __syncthreads();
#pragma unroll
    for (int i0 = 0; i0 < 64; i0 += 4) {
      f32x4 dv4 = *(const f32x4*)&dl[c * 68 + i0];
      f32x4 uv4 = *(const f32x4*)&ul[c * 68 + i0];
      f32x4 Bv4 = *(const f32x4*)&Bl[n * 68 + i0];
#pragma unroll
      for (int rr = 0; rr < 4; ++rr) {
        float dA = __expf(dv4[rr] * A_dn);
        s = fmaf(dA, s, dv4[rr] * Bv4[rr] * uv4[rr]);
        p *= dA;
      }
    }
    __syncthreads();
  }
  const int peIdx = (r * NSEG + seg) * 256 + t;
  pbuf[peIdx] = p;
  ebuf[peIdx] = s;
}

__global__ __launch_bounds__(256) void scan_part2(
    const float* __restrict__ delta,
    const _Float16* __restrict__ u16,
    const _Float16* __restrict__ xz16,   // z = xz16[:, DINNER:]
    const float* __restrict__ x_dbl,
    const float* __restrict__ A_log,
    const float* __restrict__ Dp,
    const float* __restrict__ pbuf,
    const float* __restrict__ ebuf,
    _Float16* __restrict__ y16)
{
  const int t = threadIdx.x;
  const int c = t >> 4, n = t & 15;
  const int bb = blockIdx.x;
  const int seg = bb >> 8;
  const int r = bb & 255;
  const int b = r >> 7;
  const int d_base = (r & 127) * 16;

  const float A_dn = -__expf(A_log[(d_base + c) * DSTATE + n]);

  float s = 0.f;
  {
    const int base = r * NSEG * 256 + t;
    for (int k = 0; k < seg; ++k)
      s = fmaf(pbuf[base + k * 256], s, ebuf[base + k * 256]);
  }

  __shared__ __align__(16) float dl[16 * 68];
  __shared__ __align__(16) float ul[16 * 68];
  __shared__ __align__(16) float Bl[16 * 68];
  __shared__ __align__(16) float Cl[16 * 68];
  __shared__ __align__(16) float yl[16 * 68];
  __shared__ __align__(16) float z_s[64 * 16];
  __shared__ float Dp_s[16];

  if (t < 16) Dp_s[t] = Dp[d_base + t];

  const int i_st = t >> 2;
  const int cc = (t & 3) * 4;

  for (int l0 = seg * SEGLEN; l0 < seg * SEGLEN + SEGLEN; l0 += 64) {
    const int row = b * SEQLEN + l0 + i_st;
    {
      float4 dv = *(const float4*)&delta[(size_t)row * DINNER + d_base + cc];
      f16x4  uh = *(const f16x4*)&u16[(size_t)row * DINNER + d_base + cc];
      float4 Bv = *(const float4*)&x_dbl[(size_t)row * XPAD + DTRANK + cc];
      float4 Cv = *(const float4*)&x_dbl[(size_t)row * XPAD + DTRANK + DSTATE + cc];
      f16x4  zh = *(const f16x4*)&xz16[(size_t)row * (2 * DINNER) + DINNER + d_base + cc];
      dl[(cc+0)*68 + i_st] = dv.x; dl[(cc+1)*68 + i_st] = dv.y;
      dl[(cc+2)*68 + i_st] = dv.z; dl[(cc+3)*68 + i_st] = dv.w;
      ul[(cc+0)*68 + i_st] = (float)uh[0]; ul[(cc+1)*68 + i_st] = (float)uh[1];
      ul[(cc+2)*68 + i_st] = (float)uh[2]; ul[(cc+3)*68 + i_st] = (float)uh[3];
      Bl[(cc+0)*68 + i_st] = Bv.x; Bl[(cc+1)*68 + i_st] = Bv.y;
      Bl[(cc+2)*68 + i_st] = Bv.z; Bl[(cc+3)*68 + i_st] = Bv.w;
      Cl[(cc+0)*68 + i_st] = Cv.x; Cl[(cc+1)*68 + i_st] = Cv.y;
      Cl[(cc+2)*68 + i_st] = Cv.z; Cl[(cc+3)*68 + i_st] = Cv.w;
      float4 zv = make_float4((float)zh[0], (float)zh[1], (float)zh[2], (float)zh[3]);
      *(float4*)&z_s[t * 4] = zv;
    }
    __syncthreads();

#pragma unroll
    for (int i0 = 0; i0 < 64; i0 += 4) {
      f32x4 dv4 = *(const f32x4*)&dl[c * 68 + i0];
      f32x4 uv4 = *(const f32x4*)&ul[c * 68 + i0];
      f32x4 Bv4 = *(const f32x4*)&Bl[n * 68 + i0];
      f32x4 Cv4 = *(const f32x4*)&Cl[n * 68 + i0];
      f32x4 py;
#pragma unroll
      for (int rr = 0; rr < 4; ++rr) {
        float dA = __expf(dv4[rr] * A_dn);
        s = fmaf(dA, s, dv4[rr] * Bv4[rr] * uv4[rr]);
        py[rr] = row_sum16(s * Cv4[rr]);
      }
      if (n == 0) *(f32x4*)&yl[c * 68 + i0] = py;
    }
    __syncthreads();

#pragma unroll
    for (int k = 0; k < 4; ++k) {
      int o = t + 256 * k;
      int i = o >> 4, c2 = o & 15;
      float ssum = yl[c2 * 68 + i];
      float uv = ul[c2 * 68 + i];
      float zv = z_s[o];
      float yv = fmaf(uv, Dp_s[c2], ssum);
      yv *= zv / (1.f + __expf(-zv));
      y16[(size_t)(b * SEQLEN + l0 + i) * DINNER + d_base + c2] = (_Float16)yv;
    }
    __syncthreads();
  }
}

// ---------------------------------------------------------------------------
extern "C" void kernel_launch(void* const* d_in, const int* in_sizes, int n_in,
                              void* d_out, int out_size, void* d_ws, size_t ws_size,
                              hipStream_t stream)
{
  const float* hidden     = (const float*)d_in[0];
  const float* in_proj_w  = (const float*)d_in[1];
  const float* conv_w     = (const float*)d_in[2];
  const float* conv_b     = (const float*)d_in[3];
  const float* x_proj_w   = (const float*)d_in[4];
  const float* dt_proj_w  = (const float*)d_in[5];
  const float* dt_proj_b  = (const float*)d_in[6];
  const float* A_log      = (const float*)d_in[7];
  const float* Dp         = (const float*)d_in[8];
  const float* out_proj_w = (const float*)d_in[9];
  float* out = (float*)d_out;

  char* p = (char*)d_ws;
  _Float16* xz16   = (_Float16*)p;  p += (size_t)MROWS * 2 * DINNER * 2;
  _Float16* u16    = (_Float16*)p;  p += (size_t)MROWS * DINNER * 2;
  float*    xdbl32 = (float*)p;     p += (size_t)MROWS * XPAD * 4;
  float*    delta  = (float*)p;     p += (size_t)MROWS * DINNER * 4;
  _Float16* h16    = (_Float16*)p;  p += (size_t)MROWS * DMODEL * 2;
  _Float16* win16  = (_Float16*)p;  p += (size_t)2 * DINNER * DMODEL * 2;
  _Float16* wout16 = (_Float16*)p;  p += (size_t)DMODEL * DINNER * 2;
  _Float16* wdt16  = (_Float16*)p;  p += (size_t)DINNER * DTRANK * 2;
  _Float16* wxp16  = (_Float16*)p;  p += (size_t)XPAD * DINNER * 2;
  _Float16* xdbl16 = (_Float16*)p;  p += (size_t)MROWS * DTRANK * 2;
  _Float16* y16    = (_Float16*)p;  p += (size_t)MROWS * DINNER * 2;
  float*    pbuf   = (float*)p;     p += (size_t)256 * NSEG * 256 * 4;
  float*    ebuf   = (float*)p;     p += (size_t)256 * NSEG * 256 * 4;
  // x_proj split-K partials alias delta (dead until dt-GEMM writes it):
  float*    xp_part = delta;        // 16 * 2048*128 * 4 = 16.8MB exactly

  // 0. all fp32->fp16 conversions in one launch
  f2h_all<<<(F2H_TOTAL + 255) / 256, 256, 0, stream>>>(
      hidden, in_proj_w, out_proj_w, dt_proj_w, x_proj_w,
      h16, win16, wout16, wdt16, wxp16);

  // 1. in_proj: xz16 = f16(hidden @ in_proj_w^T)  [2048, 4096], K=1024
  pgemm<4><<<dim3(2 * DINNER / 128, MROWS / 64, 1), 256, 0, stream>>>(
      h16, DMODEL, win16, DMODEL, nullptr, 2 * DINNER, DMODEL, nullptr, xz16, 0);

  // 2. conv + SiLU -> u16
  conv_silu<<<(MROWS * DINNER) / 256, 256, 0, stream>>>(xz16, conv_w, conv_b, u16);

  // 3. x_proj: partials[z] = u @ x_proj_w^T chunk  [2048,128], split-K=16
  pgemm<0><<<dim3(1, MROWS / 64, XP_SPLIT), 256, 0, stream>>>(
      u16, DINNER, wxp16, DINNER, xp_part, XPAD, DINNER, nullptr, nullptr,
      (size_t)MROWS * XPAD);

  // 3b. reduce partials -> xdbl32 + f16 dt cols
  reduce_xdbl<<<(MROWS * XPAD / 4) / 256, 256, 0, stream>>>(xp_part, xdbl32, xdbl16);

  // 4. dt: delta = softplus(xdbl16 @ dt_proj_w^T + 2*b)  [2048,2048], K=64
  pgemm<2><<<dim3(DINNER / 128, MROWS / 64, 1), 256, 0, stream>>>(
      xdbl16, DTRANK, wdt16, DTRANK, delta, DINNER, DTRANK, dt_proj_b, nullptr, 0);

  // 5. selective scan, two-pass sequence-split -> y16
  scan_part1<<<256 * NSEG, 256, 0, stream>>>(delta, u16, xdbl32, A_log, pbuf, ebuf);
  scan_part2<<<256 * NSEG, 256, 0, stream>>>(delta, u16, xz16, xdbl32, A_log, Dp,
                                             pbuf, ebuf, y16);

  // 6. out_proj: out = y @ out_proj_w^T [2048, 1024], K=2048
  pgemm<0><<<dim3(DMODEL / 128, MROWS / 64, 1), 256, 0, stream>>>(
      y16, DINNER, wout16, DINNER, out, DMODEL, DINNER, nullptr, nullptr, 0);
}